// Round 14
// baseline (298.966 us; speedup 1.0000x reference)
//
#include <hip/hip_runtime.h>
#include <math.h>

#define B_ 64
#define K_ 4000
#define G_ 200
#define C_ 91
#define EPS_ 1e-9f
#define NW_ 16
#define DEPTH_ 32
typedef unsigned long long ull;

// ws layout (byte offsets); total use ~3.6 MB
#define WS_FLAG 0
#define WS_PART 256        // 64*4 f32
#define WS_CNT 1536       // 64 int
#define WS_MATCH 2048     // 64*200 u32 (p<<8|g)
#define WS_ROWUSED 53248  // 64*4000 bytes
#define WS_TOP 327680     // 64*200*32 ull = 3.28 MB (exact top-L lists, L<=32)

// list key: (iou_bits << 12) | (4095 - p)   — iou desc, then p asc; always > 0
// full key: (list << 8) | (255 - g)         — iou desc, p asc, g asc == argmax flat order
__device__ __forceinline__ float box_area(float4 a) {
#pragma clang fp contract(off)
  return fmaxf(a.z - a.x, 0.f) * fmaxf(a.w - a.y, 0.f);
}

// IoU; contract(off) => bit-identical across init and rescan
__device__ __forceinline__ float iou_ab(float4 a, float aA, float4 b, float aB) {
#pragma clang fp contract(off)
  float tlx = fmaxf(a.x, b.x), tly = fmaxf(a.y, b.y);
  float brx = fminf(a.z, b.z), bry = fminf(a.w, b.w);
  float w = fmaxf(brx - tlx, 0.f), h = fmaxf(bry - tly, 0.f);
  float inter = w * h;
  float uni = fmaxf(aA + aB - inter, EPS_);
  return inter / uni;
}

__device__ __forceinline__ float ciou_loss(float4 p, float4 g) {
  float tlx = fmaxf(p.x, g.x), tly = fmaxf(p.y, g.y);
  float brx = fminf(p.z, g.z), bry = fminf(p.w, g.w);
  float w = fmaxf(brx - tlx, 0.f), h = fmaxf(bry - tly, 0.f);
  float inter = w * h;
  float areaP = fmaxf(p.z - p.x, 0.f) * fmaxf(p.w - p.y, 0.f);
  float areaG = fmaxf(g.z - g.x, 0.f) * fmaxf(g.w - g.y, 0.f);
  float iou = inter / fmaxf(areaP + areaG - inter, EPS_);
  float px = (p.x + p.z) * 0.5f, py = (p.y + p.w) * 0.5f;
  float tx = (g.x + g.z) * 0.5f, ty = (g.y + g.w) * 0.5f;
  float rho2 = (px - tx) * (px - tx) + (py - ty) * (py - ty);
  float ex = fmaxf(p.z, g.z) - fminf(p.x, g.x);
  float ey = fmaxf(p.w, g.w) - fminf(p.y, g.y);
  float c2 = fmaxf(ex * ex + ey * ey, EPS_);
  float pw = fmaxf(p.z - p.x, EPS_), ph = fmaxf(p.w - p.y, EPS_);
  float tw = fmaxf(g.z - g.x, EPS_), th = fmaxf(g.w - g.y, EPS_);
  float dat = atanf(tw / th) - atanf(pw / ph);
  float v = (4.0f / (float)(M_PI * M_PI)) * dat * dat;
  float alpha = v / ((1.f - iou) + v + EPS_);
  return 1.f - (iou - rho2 / c2 - alpha * v);
}

// gt_mask layout detector (int8 bool vs 4-byte elems) — unchanged (passed R1-R13)
__global__ void kdetect(const unsigned char* m8, int* flag) {
  int b = threadIdx.x;
  int ok = 1;
  const unsigned char* r = m8 + b * G_;
  if (r[0] != 1) ok = 0;
  int seen0 = 0;
  for (int g = 0; g < G_; ++g) {
    unsigned char c = r[g];
    if (c > 1) { ok = 0; break; }
    if (c == 0) seen0 = 1;
    else if (seen0) { ok = 0; break; }
  }
  int all = __all(ok);
  if (b == 0) *flag = all ? 1 : 0;
}

__device__ __forceinline__ float block_sum(float v, float* s_red) {
  for (int off = 32; off > 0; off >>= 1) v += __shfl_xor(v, off);
  int lane = threadIdx.x & 63, wid = threadIdx.x >> 6;
  if (lane == 0) s_red[wid] = v;
  __syncthreads();
  float r = 0.f;
  if (wid == 0) {
    float t = (lane < NW_) ? s_red[lane] : 0.f;
    for (int off = 32; off > 0; off >>= 1) t += __shfl_xor(t, off);
    r = t;
  }
  __syncthreads();
  return r;  // valid at tid 0
}

// one butterfly stage of wave top-4 reduce (exact; 6 stages converge all lanes)
__device__ __forceinline__ void merge4_stage(ull& v0, ull& v1, ull& v2, ull& v3,
                                             int off) {
  ull w0 = __shfl_xor(v0, off), w1 = __shfl_xor(v1, off);
  ull w2 = __shfl_xor(v2, off), w3 = __shfl_xor(v3, off);
  ull t0 = v0 > w3 ? v0 : w3;
  ull t1 = v1 > w2 ? v1 : w2;
  ull t2 = v2 > w1 ? v2 : w1;
  ull t3 = v3 > w0 ? v3 : w0;
  ull x;
  if (t2 > t0) { x = t0; t0 = t2; t2 = x; }
  if (t3 > t1) { x = t1; t1 = t3; t3 = x; }
  if (t1 > t0) { x = t0; t0 = t1; t1 = x; }
  if (t3 > t2) { x = t2; t2 = t3; t3 = x; }
  v0 = t0; v1 = t1; v2 = t2; v3 = t3;
}

// register-resident sorted-desc top-4 insert (cheap chain; exec-mask friendly)
#define TOP4_INS(key, t0, t1, t2, t3)                   \
  if ((key) > t3) {                                     \
    t3 = (key);                                         \
    ull tmp_;                                           \
    if (t3 > t2) { tmp_ = t2; t2 = t3; t3 = tmp_; }     \
    if (t2 > t1) { tmp_ = t1; t1 = t2; t2 = tmp_; }     \
    if (t1 > t0) { tmp_ = t0; t0 = t1; t1 = tmp_; }     \
  }

// rank-sort extraction (same written prefix as the R8-R12 drain-stop pops)
__device__ __forceinline__ void rank_extract(ull t0, ull t1, ull t2, ull t3,
                                             ull* dst, int lane) {
  int r0 = 0, r1 = 0, r2 = 0, r3 = 0;
  for (int i = 0; i < 64; ++i) {
    ull o0 = __shfl(t0, i), o1 = __shfl(t1, i);
    ull o2 = __shfl(t2, i), o3 = __shfl(t3, i);
    r0 += (o0 > t0) + (o1 > t0) + (o2 > t0) + (o3 > t0);
    r1 += (o0 > t1) + (o1 > t1) + (o2 > t1) + (o3 > t1);
    r2 += (o0 > t2) + (o1 > t2) + (o2 > t2) + (o3 > t2);
    r3 += (o0 > t3) + (o1 > t3) + (o2 > t3) + (o3 > t3);
  }
  int cut = (t3 != 0ull) ? (r3 + 1) : 0x7FFFFFFF;
  int nc = (t0 != 0ull) + (t1 != 0ull) + (t2 != 0ull) + (t3 != 0ull);
  for (int off = 32; off > 0; off >>= 1) {
    int oc = __shfl_xor(cut, off);
    cut = (oc < cut) ? oc : cut;
    nc += __shfl_xor(nc, off);
  }
  const int Lf = (cut < DEPTH_) ? cut : DEPTH_;
  const int zstart = (Lf < nc) ? Lf : nc;
  if (t0 != 0ull && r0 < Lf) dst[r0] = t0;
  if (t1 != 0ull && r1 < Lf) dst[r1] = t1;
  if (t2 != 0ull && r2 < Lf) dst[r2] = t2;
  if (t3 != 0ull && r3 < Lf) dst[r3] = t3;
  for (int o = lane; o < DEPTH_; o += 64)
    if (o >= zstart) dst[o] = 0ull;
}

// ---- phase 1: wave-per-column exact top-L lists; fused 2-col scan ----
__global__ __launch_bounds__(1024) void kinit(const float* __restrict__ pred_boxes,
                                              const float* __restrict__ gt_boxes,
                                              const void* __restrict__ gt_mask,
                                              char* __restrict__ ws) {
  __shared__ float4 s_p[K_];  // 64 KB staged pred boxes
  const int blk = blockIdx.x;
  const int b = blk >> 3, oct = blk & 7;
  const int tid = threadIdx.x, lane = tid & 63, wid = tid >> 6;
  const int msk8 = *(const int*)(ws + WS_FLAG);
  const float4* p4 = (const float4*)pred_boxes + (size_t)b * K_;
  const float4* g4 = (const float4*)gt_boxes + (size_t)b * G_;

  for (int i = tid; i < K_; i += 1024) s_p[i] = p4[i];
  __syncthreads();

  const int base = oct * 25;
  const int colA = base + wid;
  const int colB = base + 16 + wid;
  const bool hasB = (wid < 9);
  ull* wtop = (ull*)(ws + WS_TOP);

  int vA, vB = 0;
  if (msk8) vA = ((const unsigned char*)gt_mask)[(size_t)b * G_ + colA] != 0;
  else      vA = ((const int*)gt_mask)[(size_t)b * G_ + colA] != 0;
  if (hasB) {
    if (msk8) vB = ((const unsigned char*)gt_mask)[(size_t)b * G_ + colB] != 0;
    else      vB = ((const int*)gt_mask)[(size_t)b * G_ + colB] != 0;
  }

  float4 gbA, gbB;
  float gAA = 0.f, gAB = 0.f;
  if (vA) { gbA = g4[colA]; gAA = box_area(gbA); }
  if (vB) { gbB = g4[colB]; gAB = box_area(gbB); }

  ull a0 = 0, a1 = 0, a2 = 0, a3 = 0;
  ull b0 = 0, b1 = 0, b2 = 0, b3 = 0;
  if (vA | vB) {
#pragma unroll 2
    for (int k = lane; k < K_; k += 64) {
      float4 pb = s_p[k];
      float ar = box_area(pb);
      if (vA) {
        float iou = iou_ab(pb, ar, gbA, gAA);
        ull e = ((ull)__float_as_uint(iou) << 12) | (ull)(4095 - k);
        TOP4_INS(e, a0, a1, a2, a3);
      }
      if (vB) {
        float iou = iou_ab(pb, ar, gbB, gAB);
        ull e = ((ull)__float_as_uint(iou) << 12) | (ull)(4095 - k);
        TOP4_INS(e, b0, b1, b2, b3);
      }
    }
  }
  {
    ull* dstA = wtop + ((size_t)b * G_ + colA) * DEPTH_;
    if (vA) rank_extract(a0, a1, a2, a3, dstA, lane);
    else    for (int o = lane; o < DEPTH_; o += 64) dstA[o] = 0ull;
  }
  if (hasB) {
    ull* dstB = wtop + ((size_t)b * G_ + colB) * DEPTH_;
    if (vB) rank_extract(b0, b1, b2, b3, dstB, lane);
    else    for (int o = lane; o < DEPTH_; o += 64) dstB[o] = 0ull;
  }
}

// ---- phase 2: greedy matching, 1 wave/batch, quad-pop (isolated dispatch) ----
__global__ __launch_bounds__(64) void kmatch(const float* __restrict__ pred_boxes,
                                             const float* __restrict__ gt_boxes,
                                             char* __restrict__ ws) {
  __shared__ float s_gx[G_], s_gy[G_], s_gz[G_], s_gw[G_], s_garea[G_];
  __shared__ unsigned char s_rowused[4096];
  __shared__ ull s_tlkey[G_][DEPTH_ + 1];           // stride 33: bank-spread
  __shared__ unsigned short s_tlrow[G_][DEPTH_ + 1]; // decoded rows for walks
  __shared__ int s_mp[G_];
  __shared__ unsigned short s_mg[G_];
  const int b = blockIdx.x;
  const int lane = threadIdx.x;
  const float4* p4 = (const float4*)pred_boxes + (size_t)b * K_;
  const float4* g4 = (const float4*)gt_boxes + (size_t)b * G_;
  const ull* wtop = (const ull*)(ws + WS_TOP);

  for (int g = lane; g < G_; g += 64) {
    float4 gb = g4[g];
    s_gx[g] = gb.x; s_gy[g] = gb.y; s_gz[g] = gb.z; s_gw[g] = gb.w;
    s_garea[g] = box_area(gb);
  }
  for (int k = lane; k < 4096; k += 64) s_rowused[k] = 0;
  for (int i = lane; i < G_ * DEPTH_; i += 64) {
    ull v = wtop[(size_t)b * G_ * DEPTH_ + i];
    int col = i / DEPTH_, o = i % DEPTH_;
    s_tlkey[col][o] = v;
    s_tlrow[col][o] = v ? (unsigned short)(4095 - (int)((v >> 12) & 0xFFF))
                        : (unsigned short)0xFFFF;
  }
  __builtin_amdgcn_wave_barrier();

  ull key0 = 0, key1 = 0, key2 = 0, key3 = 0;
  int ptr0 = DEPTH_, ptr1 = DEPTH_, ptr2 = DEPTH_, ptr3 = DEPTH_;
  int cloc = 0;
#define SLOTINIT(S)                                                        \
  { int col = S * 64 + lane;                                               \
    if (col < G_) {                                                        \
      ull h_ = s_tlkey[col][0];                                            \
      if (h_ != 0ull) {                                                    \
        key##S = (h_ << 8) | (ull)(255 - col); ptr##S = 1; ++cloc; } } }
  SLOTINIT(0) SLOTINIT(1) SLOTINIT(2) SLOTINIT(3)
#undef SLOTINIT
  for (int off = 32; off > 0; off >>= 1) cloc += __shfl_xor(cloc, off);
  const int cnt = cloc;

  for (int step = 0; step < cnt;) {
    // lane-local sorted-desc 4-list of slot keys (5-comparator network)
    ull v0 = key0, v1 = key1, v2 = key2, v3 = key3, x;
    if (v1 > v0) { x = v0; v0 = v1; v1 = x; }
    if (v3 > v2) { x = v2; v2 = v3; v3 = x; }
    if (v2 > v0) { x = v0; v0 = v2; v2 = x; }
    if (v3 > v1) { x = v1; v1 = v3; v3 = x; }
    if (v2 > v1) { x = v1; v1 = v2; v2 = x; }
    merge4_stage(v0, v1, v2, v3, 32);
    merge4_stage(v0, v1, v2, v3, 16);
    merge4_stage(v0, v1, v2, v3, 8);
    merge4_stage(v0, v1, v2, v3, 4);
    merge4_stage(v0, v1, v2, v3, 2);
    merge4_stage(v0, v1, v2, v3, 1);
    const int P0 = 4095 - (int)((v0 >> 8) & 0xFFF), G0 = 255 - (int)(v0 & 0xFF);
    const int P1 = 4095 - (int)((v1 >> 8) & 0xFFF), G1 = 255 - (int)(v1 & 0xFF);
    const int P2 = 4095 - (int)((v2 >> 8) & 0xFFF), G2 = 255 - (int)(v2 & 0xFF);
    const int P3 = 4095 - (int)((v3 >> 8) & 0xFFF), G3 = 255 - (int)(v3 & 0xFF);
    // accept maximal prefix with pairwise-distinct rows (proof in R12; exact)
    const int lim = cnt - step;
    const bool a2 = (v1 != 0ull) && (P1 != P0) && (lim > 1);
    const bool a3 = a2 && (v2 != 0ull) && (P2 != P0) && (P2 != P1) && (lim > 2);
    const bool a4 = a3 && (v3 != 0ull) && (P3 != P0) && (P3 != P1) && (P3 != P2) && (lim > 3);
    const int nacc = 1 + (int)a2 + (int)a3 + (int)a4;
    if (lane == 0) {
      s_mp[step] = P0; s_mg[step] = (unsigned short)G0; s_rowused[P0] = 1;
      if (a2) { s_mp[step + 1] = P1; s_mg[step + 1] = (unsigned short)G1; s_rowused[P1] = 1; }
      if (a3) { s_mp[step + 2] = P2; s_mg[step + 2] = (unsigned short)G2; s_rowused[P2] = 1; }
      if (a4) { s_mp[step + 3] = P3; s_mg[step + 3] = (unsigned short)G3; s_rowused[P3] = 1; }
    }
    __builtin_amdgcn_wave_barrier();
    const int gA = G0, gB = a2 ? G1 : -1, gC = a3 ? G2 : -1, gD = a4 ? G3 : -1;
    const int pA = P0, pB = a2 ? P1 : -1, pC = a3 ? P2 : -1, pD = a4 ? P3 : -1;
    int need = 0;
#define DEMOTE(S)                                                           \
    { int col = S * 64 + lane; ull kk = key##S;                             \
      if (kk != 0ull) {                                                     \
        if (col == gA || col == gB || col == gC || col == gD) {             \
          key##S = 0ull;                                                    \
        } else {                                                            \
          int krow = 4095 - (int)((kk >> 8) & 0xFFF);                       \
          if (krow == pA || krow == pB || krow == pC || krow == pD) {       \
            ull nk = 0ull; int np = ptr##S;                                 \
            while (np < DEPTH_) {                                           \
              int r_ = s_tlrow[col][np];                                    \
              if (r_ == 0xFFFF) { np = DEPTH_; break; }                     \
              if (!s_rowused[r_]) {                                         \
                nk = (s_tlkey[col][np] << 8) | (ull)(255 - col);            \
                ++np; break;                                                \
              }                                                             \
              ++np;                                                         \
            }                                                               \
            ptr##S = np; key##S = nk;                                       \
            if (nk == 0ull) need |= (1 << S); } } } }
    DEMOTE(0) DEMOTE(1) DEMOTE(2) DEMOTE(3)
#undef DEMOTE
    // exact fallback: full rescan over unused rows; rank-sort refill
    while (__any(need)) {
      unsigned long long bal = __ballot(need != 0);
      int src = (int)__builtin_ctzll(bal);
      int myslot = need ? __builtin_ctz(need) : 0;
      int slot = __shfl(myslot, src);
      int col = slot * 64 + src;
      float4 gb = make_float4(s_gx[col], s_gy[col], s_gz[col], s_gw[col]);
      float gA2 = s_garea[col];
      ull t0 = 0, t1 = 0, t2 = 0, t3 = 0;
#pragma unroll 2
      for (int k = lane; k < K_; k += 64) {
        if (!s_rowused[k]) {
          float4 pb = p4[k];
          float iou = iou_ab(pb, box_area(pb), gb, gA2);
          ull e = ((ull)__float_as_uint(iou) << 12) | (ull)(4095 - k);
          TOP4_INS(e, t0, t1, t2, t3);
        }
      }
      int r0 = 0, r1 = 0, r2 = 0, r3 = 0;
      for (int i = 0; i < 64; ++i) {
        ull o0 = __shfl(t0, i), o1 = __shfl(t1, i);
        ull o2 = __shfl(t2, i), o3 = __shfl(t3, i);
        r0 += (o0 > t0) + (o1 > t0) + (o2 > t0) + (o3 > t0);
        r1 += (o0 > t1) + (o1 > t1) + (o2 > t1) + (o3 > t1);
        r2 += (o0 > t2) + (o1 > t2) + (o2 > t2) + (o3 > t2);
        r3 += (o0 > t3) + (o1 > t3) + (o2 > t3) + (o3 > t3);
      }
      int cut = (t3 != 0ull) ? (r3 + 1) : 0x7FFFFFFF;
      int nc = (t0 != 0ull) + (t1 != 0ull) + (t2 != 0ull) + (t3 != 0ull);
      for (int off = 32; off > 0; off >>= 1) {
        int oc = __shfl_xor(cut, off);
        cut = (oc < cut) ? oc : cut;
        nc += __shfl_xor(nc, off);
      }
      const int Lf = (cut < DEPTH_) ? cut : DEPTH_;
      const int zstart = (Lf < nc) ? Lf : nc;
      if (t0 != 0ull && r0 < Lf) {
        s_tlkey[col][r0] = t0;
        s_tlrow[col][r0] = (unsigned short)(4095 - (int)((t0 >> 12) & 0xFFF));
      }
      if (t1 != 0ull && r1 < Lf) {
        s_tlkey[col][r1] = t1;
        s_tlrow[col][r1] = (unsigned short)(4095 - (int)((t1 >> 12) & 0xFFF));
      }
      if (t2 != 0ull && r2 < Lf) {
        s_tlkey[col][r2] = t2;
        s_tlrow[col][r2] = (unsigned short)(4095 - (int)((t2 >> 12) & 0xFFF));
      }
      if (t3 != 0ull && r3 < Lf) {
        s_tlkey[col][r3] = t3;
        s_tlrow[col][r3] = (unsigned short)(4095 - (int)((t3 >> 12) & 0xFFF));
      }
      for (int o = lane; o < DEPTH_; o += 64)
        if (o >= zstart) { s_tlkey[col][o] = 0ull; s_tlrow[col][o] = 0xFFFF; }
      __builtin_amdgcn_wave_barrier();
      ull newhead = s_tlkey[col][0];
      if (lane == src) {
        ull nk = (newhead << 8) | (ull)(255 - col);
        if (slot == 0) { key0 = nk; ptr0 = 1; }
        else if (slot == 1) { key1 = nk; ptr1 = 1; }
        else if (slot == 2) { key2 = nk; ptr2 = 1; }
        else { key3 = nk; ptr3 = 1; }
        need &= ~(1 << slot);
      }
      __builtin_amdgcn_wave_barrier();
    }
    step += nacc;
  }

  // dump results for kepi
  unsigned* mout = (unsigned*)(ws + WS_MATCH) + b * G_;
  for (int i = lane; i < cnt; i += 64)
    mout[i] = ((unsigned)s_mp[i] << 8) | (unsigned)s_mg[i];
  unsigned* ruo = (unsigned*)(ws + WS_ROWUSED + (size_t)b * K_);
  const unsigned* rus = (const unsigned*)s_rowused;
  for (int i = lane; i < K_ / 4; i += 64) ruo[i] = rus[i];
  if (lane == 0) ((int*)(ws + WS_CNT))[b] = cnt;
}

// ---- phase 3: CIoU + CE over matches, BCE objectness over all K ----
__global__ __launch_bounds__(1024) void kepi(const float* __restrict__ pred_boxes,
                                             const float* __restrict__ obj_logits,
                                             const float* __restrict__ cls_logits,
                                             const float* __restrict__ gt_boxes,
                                             const int* __restrict__ gt_labels,
                                             char* __restrict__ ws) {
  __shared__ float s_red[NW_];
  const int b = blockIdx.x;
  const int tid = threadIdx.x;
  const int cnt = ((const int*)(ws + WS_CNT))[b];
  const unsigned* mm = (const unsigned*)(ws + WS_MATCH) + b * G_;
  const unsigned char* ru = (const unsigned char*)(ws + WS_ROWUSED) + (size_t)b * K_;
  const float4* p4 = (const float4*)pred_boxes + (size_t)b * K_;
  const float4* g4 = (const float4*)gt_boxes + (size_t)b * G_;

  float lbox = 0.f, lcls = 0.f;
  for (int i = tid; i < cnt; i += 1024) {
    unsigned e = mm[i];
    int p = (int)(e >> 8), g = (int)(e & 0xFF);
    float4 pb = p4[p];
    float4 gb = g4[g];
    lbox += ciou_loss(pb, gb);
    int label = gt_labels[(size_t)b * G_ + g];
    const float* lg = cls_logits + ((size_t)b * K_ + p) * C_;
    float m = -1e30f;
    for (int cc = 0; cc < C_; ++cc) m = fmaxf(m, lg[cc]);
    float s = 0.f;
    for (int cc = 0; cc < C_; ++cc) s += expf(lg[cc] - m);
    lcls += (m + logf(s)) - lg[label];
  }
  float obj = 0.f;
  const float* ol = obj_logits + (size_t)b * K_;
  for (int k = tid; k < K_; k += 1024) {
    float x = ol[k];
    float sp = fmaxf(x, 0.f) + log1pf(expf(-fabsf(x)));  // softplus(x)
    if (ru[k]) sp -= x;                                  // - t*x
    obj += sp;
  }
  lbox = block_sum(lbox, s_red);
  lcls = block_sum(lcls, s_red);
  obj = block_sum(obj, s_red);
  if (tid == 0) {
    float* partials = (float*)(ws + WS_PART);
    float n = (float)cnt;
    float denom = fmaxf(n, 1.f);
    partials[b * 4 + 0] = lbox / denom;
    partials[b * 4 + 1] = lcls / denom;
    partials[b * 4 + 2] = obj;
    partials[b * 4 + 3] = (n > 0.f) ? 1.f : 0.f;
  }
}

__global__ void kfinal(const char* __restrict__ ws, float* __restrict__ out) {
  int b = threadIdx.x;  // 64 threads, one wave
  const float* partials = (const float*)(ws + WS_PART);
  float lb = partials[b * 4 + 0], lc = partials[b * 4 + 1];
  float ob = partials[b * 4 + 2], hf = partials[b * 4 + 3];
  float sb = lb * hf, sc = lc * hf, sh = hf, so = ob;
  for (int off = 32; off > 0; off >>= 1) {
    sb += __shfl_xor(sb, off);
    sc += __shfl_xor(sc, off);
    sh += __shfl_xor(sh, off);
    so += __shfl_xor(so, off);
  }
  if (b == 0) {
    float nb = fmaxf(sh, 1.f);
    float box = sb / nb, cls = sc / nb;
    float obj = so / (float)(B_ * K_);
    out[0] = 5.f * box + cls + obj;
    out[1] = box;
    out[2] = cls;
    out[3] = obj;
  }
}

extern "C" void kernel_launch(void* const* d_in, const int* in_sizes, int n_in,
                              void* d_out, int out_size, void* d_ws, size_t ws_size,
                              hipStream_t stream) {
  const float* pred_boxes = (const float*)d_in[0];
  const float* obj_logits = (const float*)d_in[1];
  const float* cls_logits = (const float*)d_in[2];
  const float* gt_boxes = (const float*)d_in[3];
  const int* gt_labels = (const int*)d_in[4];
  const void* gt_mask = d_in[5];
  float* out = (float*)d_out;
  char* ws = (char*)d_ws;

  hipLaunchKernelGGL(kdetect, dim3(1), dim3(64), 0, stream,
                     (const unsigned char*)gt_mask, (int*)(ws + WS_FLAG));
  hipLaunchKernelGGL(kinit, dim3(B_ * 8), dim3(1024), 0, stream,
                     pred_boxes, gt_boxes, gt_mask, ws);
  hipLaunchKernelGGL(kmatch, dim3(B_), dim3(64), 0, stream,
                     pred_boxes, gt_boxes, ws);
  hipLaunchKernelGGL(kepi, dim3(B_), dim3(1024), 0, stream,
                     pred_boxes, obj_logits, cls_logits, gt_boxes, gt_labels, ws);
  hipLaunchKernelGGL(kfinal, dim3(1), dim3(64), 0, stream, ws, out);
}

// Round 15
// 293.188 us; speedup vs baseline: 1.0197x; 1.0197x over previous
//
#include <hip/hip_runtime.h>
#include <math.h>

#define B_ 64
#define K_ 4000
#define G_ 200
#define C_ 91
#define EPS_ 1e-9f
#define NW_ 16
#define DEPTH_ 32
typedef unsigned long long ull;

// ws layout (byte offsets); total use ~3.3 MB
#define WS_FLAG 0
#define WS_PART 256   // 64*4 f32
#define WS_TOP 65536  // 64*200*32 ull = 3.28 MB (exact top-L lists, L<=32)

// list key: (iou_bits << 12) | (4095 - p)   — iou desc, then p asc; always > 0
// full key: (list << 8) | (255 - g)         — iou desc, p asc, g asc == argmax flat order
__device__ __forceinline__ float box_area(float4 a) {
#pragma clang fp contract(off)
  return fmaxf(a.z - a.x, 0.f) * fmaxf(a.w - a.y, 0.f);
}

// IoU; contract(off) => bit-identical across init and rescan
__device__ __forceinline__ float iou_ab(float4 a, float aA, float4 b, float aB) {
#pragma clang fp contract(off)
  float tlx = fmaxf(a.x, b.x), tly = fmaxf(a.y, b.y);
  float brx = fminf(a.z, b.z), bry = fminf(a.w, b.w);
  float w = fmaxf(brx - tlx, 0.f), h = fmaxf(bry - tly, 0.f);
  float inter = w * h;
  float uni = fmaxf(aA + aB - inter, EPS_);
  return inter / uni;
}

__device__ __forceinline__ float ciou_loss(float4 p, float4 g) {
  float tlx = fmaxf(p.x, g.x), tly = fmaxf(p.y, g.y);
  float brx = fminf(p.z, g.z), bry = fminf(p.w, g.w);
  float w = fmaxf(brx - tlx, 0.f), h = fmaxf(bry - tly, 0.f);
  float inter = w * h;
  float areaP = fmaxf(p.z - p.x, 0.f) * fmaxf(p.w - p.y, 0.f);
  float areaG = fmaxf(g.z - g.x, 0.f) * fmaxf(g.w - g.y, 0.f);
  float iou = inter / fmaxf(areaP + areaG - inter, EPS_);
  float px = (p.x + p.z) * 0.5f, py = (p.y + p.w) * 0.5f;
  float tx = (g.x + g.z) * 0.5f, ty = (g.y + g.w) * 0.5f;
  float rho2 = (px - tx) * (px - tx) + (py - ty) * (py - ty);
  float ex = fmaxf(p.z, g.z) - fminf(p.x, g.x);
  float ey = fmaxf(p.w, g.w) - fminf(p.y, g.y);
  float c2 = fmaxf(ex * ex + ey * ey, EPS_);
  float pw = fmaxf(p.z - p.x, EPS_), ph = fmaxf(p.w - p.y, EPS_);
  float tw = fmaxf(g.z - g.x, EPS_), th = fmaxf(g.w - g.y, EPS_);
  float dat = atanf(tw / th) - atanf(pw / ph);
  float v = (4.0f / (float)(M_PI * M_PI)) * dat * dat;
  float alpha = v / ((1.f - iou) + v + EPS_);
  return 1.f - (iou - rho2 / c2 - alpha * v);
}

// gt_mask layout detector (int8 bool vs 4-byte elems) — unchanged (passed R1-R14)
__global__ void kdetect(const unsigned char* m8, int* flag) {
  int b = threadIdx.x;
  int ok = 1;
  const unsigned char* r = m8 + b * G_;
  if (r[0] != 1) ok = 0;
  int seen0 = 0;
  for (int g = 0; g < G_; ++g) {
    unsigned char c = r[g];
    if (c > 1) { ok = 0; break; }
    if (c == 0) seen0 = 1;
    else if (seen0) { ok = 0; break; }
  }
  int all = __all(ok);
  if (b == 0) *flag = all ? 1 : 0;
}

__device__ __forceinline__ float block_sum(float v, float* s_red) {
  for (int off = 32; off > 0; off >>= 1) v += __shfl_xor(v, off);
  int lane = threadIdx.x & 63, wid = threadIdx.x >> 6;
  if (lane == 0) s_red[wid] = v;
  __syncthreads();
  float r = 0.f;
  if (wid == 0) {
    float t = (lane < NW_) ? s_red[lane] : 0.f;
    for (int off = 32; off > 0; off >>= 1) t += __shfl_xor(t, off);
    r = t;
  }
  __syncthreads();
  return r;  // valid at tid 0
}

// one butterfly stage of wave top-4 reduce (exact; 6 stages converge all lanes)
__device__ __forceinline__ void merge4_stage(ull& v0, ull& v1, ull& v2, ull& v3,
                                             int off) {
  ull w0 = __shfl_xor(v0, off), w1 = __shfl_xor(v1, off);
  ull w2 = __shfl_xor(v2, off), w3 = __shfl_xor(v3, off);
  ull t0 = v0 > w3 ? v0 : w3;
  ull t1 = v1 > w2 ? v1 : w2;
  ull t2 = v2 > w1 ? v2 : w1;
  ull t3 = v3 > w0 ? v3 : w0;
  ull x;
  if (t2 > t0) { x = t0; t0 = t2; t2 = x; }
  if (t3 > t1) { x = t1; t1 = t3; t3 = x; }
  if (t1 > t0) { x = t0; t0 = t1; t1 = x; }
  if (t3 > t2) { x = t2; t2 = t3; t3 = x; }
  v0 = t0; v1 = t1; v2 = t2; v3 = t3;
}

// register-resident sorted-desc top-4 insert (cheap chain; exec-mask friendly)
#define TOP4_INS(key, t0, t1, t2, t3)                   \
  if ((key) > t3) {                                     \
    t3 = (key);                                         \
    ull tmp_;                                           \
    if (t3 > t2) { tmp_ = t2; t2 = t3; t3 = tmp_; }     \
    if (t2 > t1) { tmp_ = t1; t1 = t2; t2 = tmp_; }     \
    if (t1 > t0) { tmp_ = t0; t0 = t1; t1 = tmp_; }     \
  }

// rank-sort extraction (same written prefix as the R8-R12 drain-stop pops)
__device__ __forceinline__ void rank_extract(ull t0, ull t1, ull t2, ull t3,
                                             ull* dst, int lane) {
  int r0 = 0, r1 = 0, r2 = 0, r3 = 0;
  for (int i = 0; i < 64; ++i) {
    ull o0 = __shfl(t0, i), o1 = __shfl(t1, i);
    ull o2 = __shfl(t2, i), o3 = __shfl(t3, i);
    r0 += (o0 > t0) + (o1 > t0) + (o2 > t0) + (o3 > t0);
    r1 += (o0 > t1) + (o1 > t1) + (o2 > t1) + (o3 > t1);
    r2 += (o0 > t2) + (o1 > t2) + (o2 > t2) + (o3 > t2);
    r3 += (o0 > t3) + (o1 > t3) + (o2 > t3) + (o3 > t3);
  }
  int cut = (t3 != 0ull) ? (r3 + 1) : 0x7FFFFFFF;
  int nc = (t0 != 0ull) + (t1 != 0ull) + (t2 != 0ull) + (t3 != 0ull);
  for (int off = 32; off > 0; off >>= 1) {
    int oc = __shfl_xor(cut, off);
    cut = (oc < cut) ? oc : cut;
    nc += __shfl_xor(nc, off);
  }
  const int Lf = (cut < DEPTH_) ? cut : DEPTH_;
  const int zstart = (Lf < nc) ? Lf : nc;
  if (t0 != 0ull && r0 < Lf) dst[r0] = t0;
  if (t1 != 0ull && r1 < Lf) dst[r1] = t1;
  if (t2 != 0ull && r2 < Lf) dst[r2] = t2;
  if (t3 != 0ull && r3 < Lf) dst[r3] = t3;
  for (int o = lane; o < DEPTH_; o += 64)
    if (o >= zstart) dst[o] = 0ull;
}

// ---- phase 1: wave-per-column-pair, no LDS, load-balanced by construction ----
// grid: 400 blocks x 1024 = 6400 waves; wave w = (batch w/100, cols 2j,2j+1).
// Invalid columns exit instantly; pred read coalesced from global (L2-resident).
// List bytes identical to the R14 kinit (same per-lane top-4 + rank_extract).
__global__ __launch_bounds__(1024) void kinit(const float* __restrict__ pred_boxes,
                                              const float* __restrict__ gt_boxes,
                                              const void* __restrict__ gt_mask,
                                              char* __restrict__ ws) {
  const int wv = blockIdx.x * 16 + (threadIdx.x >> 6);
  const int lane = threadIdx.x & 63;
  const int b = wv / 100, j = wv - 100 * b;
  const int c0 = 2 * j, c1 = 2 * j + 1;
  const int msk8 = *(const int*)(ws + WS_FLAG);
  const float4* p4 = (const float4*)pred_boxes + (size_t)b * K_;
  const float4* g4 = (const float4*)gt_boxes + (size_t)b * G_;

  int vA, vB;
  if (msk8) {
    vA = ((const unsigned char*)gt_mask)[(size_t)b * G_ + c0] != 0;
    vB = ((const unsigned char*)gt_mask)[(size_t)b * G_ + c1] != 0;
  } else {
    vA = ((const int*)gt_mask)[(size_t)b * G_ + c0] != 0;
    vB = ((const int*)gt_mask)[(size_t)b * G_ + c1] != 0;
  }
  if (!(vA | vB)) return;

  float4 gbA, gbB;
  float gAA = 0.f, gAB = 0.f;
  if (vA) { gbA = g4[c0]; gAA = box_area(gbA); }
  if (vB) { gbB = g4[c1]; gAB = box_area(gbB); }

  ull a0 = 0, a1 = 0, a2 = 0, a3 = 0;
  ull b0 = 0, b1 = 0, b2 = 0, b3 = 0;
#pragma unroll 4
  for (int k = lane; k < K_; k += 64) {
    float4 pb = p4[k];
    float ar = box_area(pb);  // shared by both columns
    if (vA) {
      float iou = iou_ab(pb, ar, gbA, gAA);
      ull e = ((ull)__float_as_uint(iou) << 12) | (ull)(4095 - k);
      TOP4_INS(e, a0, a1, a2, a3);
    }
    if (vB) {
      float iou = iou_ab(pb, ar, gbB, gAB);
      ull e = ((ull)__float_as_uint(iou) << 12) | (ull)(4095 - k);
      TOP4_INS(e, b0, b1, b2, b3);
    }
  }
  ull* wtop = (ull*)(ws + WS_TOP);
  if (vA) rank_extract(a0, a1, a2, a3, wtop + ((size_t)b * G_ + c0) * DEPTH_, lane);
  if (vB) rank_extract(b0, b1, b2, b3, wtop + ((size_t)b * G_ + c1) * DEPTH_, lane);
}

// ---- phase 2+3 fused: greedy matching (wave 0, quad-pop) + epilogue ----
__global__ __launch_bounds__(1024) void kmerged(
    const float* __restrict__ pred_boxes, const float* __restrict__ obj_logits,
    const float* __restrict__ cls_logits, const float* __restrict__ gt_boxes,
    const int* __restrict__ gt_labels, const void* __restrict__ gt_mask,
    char* __restrict__ ws) {
  __shared__ float s_gx[G_], s_gy[G_], s_gz[G_], s_gw[G_], s_garea[G_];
  __shared__ unsigned char s_valid[G_];
  __shared__ unsigned char s_rowused[4096];
  __shared__ ull s_tlkey[G_][DEPTH_ + 1];            // stride 33: bank-spread
  __shared__ unsigned short s_tlrow[G_][DEPTH_ + 1]; // decoded rows for walks
  __shared__ int s_mp[G_];
  __shared__ unsigned short s_mg[G_];
  __shared__ int s_cnt;
  __shared__ float s_red[NW_];
  const int b = blockIdx.x;
  const int tid = threadIdx.x, lane = tid & 63, wid = tid >> 6;
  const int msk8 = *(const int*)(ws + WS_FLAG);
  const float4* p4 = (const float4*)pred_boxes + (size_t)b * K_;
  const float4* g4 = (const float4*)gt_boxes + (size_t)b * G_;
  const ull* wtop = (const ull*)(ws + WS_TOP);

  for (int g = tid; g < G_; g += 1024) {
    float4 gb = g4[g];
    s_gx[g] = gb.x; s_gy[g] = gb.y; s_gz[g] = gb.z; s_gw[g] = gb.w;
    s_garea[g] = box_area(gb);
    int v;
    if (msk8) v = ((const unsigned char*)gt_mask)[(size_t)b * G_ + g] != 0;
    else      v = ((const int*)gt_mask)[(size_t)b * G_ + g] != 0;
    s_valid[g] = (unsigned char)v;
  }
  for (int k = tid; k < 4096; k += 1024) s_rowused[k] = 0;
  __syncthreads();
  // staging: mask invalid columns (their ws lists are unwritten/poisoned)
  for (int i = tid; i < G_ * DEPTH_; i += 1024) {
    int col = i >> 5, o = i & 31;
    ull v = s_valid[col] ? wtop[(size_t)b * G_ * DEPTH_ + i] : 0ull;
    s_tlkey[col][o] = v;
    s_tlrow[col][o] = v ? (unsigned short)(4095 - (int)((v >> 12) & 0xFFF))
                        : (unsigned short)0xFFFF;
  }
  __syncthreads();

  if (wid == 0) {
    ull key0 = 0, key1 = 0, key2 = 0, key3 = 0;
    int ptr0 = DEPTH_, ptr1 = DEPTH_, ptr2 = DEPTH_, ptr3 = DEPTH_;
    int cloc = 0;
#define SLOTINIT(S)                                                        \
    { int col = S * 64 + lane;                                             \
      if (col < G_) {                                                      \
        ull h_ = s_tlkey[col][0];                                          \
        if (h_ != 0ull) {                                                  \
          key##S = (h_ << 8) | (ull)(255 - col); ptr##S = 1; ++cloc; } } }
    SLOTINIT(0) SLOTINIT(1) SLOTINIT(2) SLOTINIT(3)
#undef SLOTINIT
    for (int off = 32; off > 0; off >>= 1) cloc += __shfl_xor(cloc, off);
    const int cnt = cloc;
    if (lane == 0) s_cnt = cnt;

    for (int step = 0; step < cnt;) {
      // lane-local sorted-desc 4-list of slot keys (5-comparator network)
      ull v0 = key0, v1 = key1, v2 = key2, v3 = key3, x;
      if (v1 > v0) { x = v0; v0 = v1; v1 = x; }
      if (v3 > v2) { x = v2; v2 = v3; v3 = x; }
      if (v2 > v0) { x = v0; v0 = v2; v2 = x; }
      if (v3 > v1) { x = v1; v1 = v3; v3 = x; }
      if (v2 > v1) { x = v1; v1 = v2; v2 = x; }
      merge4_stage(v0, v1, v2, v3, 32);
      merge4_stage(v0, v1, v2, v3, 16);
      merge4_stage(v0, v1, v2, v3, 8);
      merge4_stage(v0, v1, v2, v3, 4);
      merge4_stage(v0, v1, v2, v3, 2);
      merge4_stage(v0, v1, v2, v3, 1);
      const int P0 = 4095 - (int)((v0 >> 8) & 0xFFF), G0 = 255 - (int)(v0 & 0xFF);
      const int P1 = 4095 - (int)((v1 >> 8) & 0xFFF), G1 = 255 - (int)(v1 & 0xFF);
      const int P2 = 4095 - (int)((v2 >> 8) & 0xFFF), G2 = 255 - (int)(v2 & 0xFF);
      const int P3 = 4095 - (int)((v3 >> 8) & 0xFFF), G3 = 255 - (int)(v3 & 0xFF);
      // accept maximal prefix with pairwise-distinct rows (proof in R12; exact)
      const int lim = cnt - step;
      const bool a2 = (v1 != 0ull) && (P1 != P0) && (lim > 1);
      const bool a3 = a2 && (v2 != 0ull) && (P2 != P0) && (P2 != P1) && (lim > 2);
      const bool a4 = a3 && (v3 != 0ull) && (P3 != P0) && (P3 != P1) && (P3 != P2) && (lim > 3);
      const int nacc = 1 + (int)a2 + (int)a3 + (int)a4;
      if (lane == 0) {
        s_mp[step] = P0; s_mg[step] = (unsigned short)G0; s_rowused[P0] = 1;
        if (a2) { s_mp[step + 1] = P1; s_mg[step + 1] = (unsigned short)G1; s_rowused[P1] = 1; }
        if (a3) { s_mp[step + 2] = P2; s_mg[step + 2] = (unsigned short)G2; s_rowused[P2] = 1; }
        if (a4) { s_mp[step + 3] = P3; s_mg[step + 3] = (unsigned short)G3; s_rowused[P3] = 1; }
      }
      __builtin_amdgcn_wave_barrier();
      const int gA = G0, gB = a2 ? G1 : -1, gC = a3 ? G2 : -1, gD = a4 ? G3 : -1;
      const int pA = P0, pB = a2 ? P1 : -1, pC = a3 ? P2 : -1, pD = a4 ? P3 : -1;
      int need = 0;
#define DEMOTE(S)                                                           \
      { int col = S * 64 + lane; ull kk = key##S;                           \
        if (kk != 0ull) {                                                   \
          if (col == gA || col == gB || col == gC || col == gD) {           \
            key##S = 0ull;                                                  \
          } else {                                                          \
            int krow = 4095 - (int)((kk >> 8) & 0xFFF);                     \
            if (krow == pA || krow == pB || krow == pC || krow == pD) {     \
              ull nk = 0ull; int np = ptr##S;                               \
              while (np < DEPTH_) {                                         \
                int r_ = s_tlrow[col][np];                                  \
                if (r_ == 0xFFFF) { np = DEPTH_; break; }                   \
                if (!s_rowused[r_]) {                                       \
                  nk = (s_tlkey[col][np] << 8) | (ull)(255 - col);          \
                  ++np; break;                                              \
                }                                                           \
                ++np;                                                       \
              }                                                             \
              ptr##S = np; key##S = nk;                                     \
              if (nk == 0ull) need |= (1 << S); } } } }
      DEMOTE(0) DEMOTE(1) DEMOTE(2) DEMOTE(3)
#undef DEMOTE
      // exact fallback: full rescan over unused rows; rank-sort refill
      while (__any(need)) {
        unsigned long long bal = __ballot(need != 0);
        int src = (int)__builtin_ctzll(bal);
        int myslot = need ? __builtin_ctz(need) : 0;
        int slot = __shfl(myslot, src);
        int col = slot * 64 + src;
        float4 gb = make_float4(s_gx[col], s_gy[col], s_gz[col], s_gw[col]);
        float gA2 = s_garea[col];
        ull t0 = 0, t1 = 0, t2 = 0, t3 = 0;
#pragma unroll 2
        for (int k = lane; k < K_; k += 64) {
          if (!s_rowused[k]) {
            float4 pb = p4[k];
            float iou = iou_ab(pb, box_area(pb), gb, gA2);
            ull e = ((ull)__float_as_uint(iou) << 12) | (ull)(4095 - k);
            TOP4_INS(e, t0, t1, t2, t3);
          }
        }
        int r0 = 0, r1 = 0, r2 = 0, r3 = 0;
        for (int i = 0; i < 64; ++i) {
          ull o0 = __shfl(t0, i), o1 = __shfl(t1, i);
          ull o2 = __shfl(t2, i), o3 = __shfl(t3, i);
          r0 += (o0 > t0) + (o1 > t0) + (o2 > t0) + (o3 > t0);
          r1 += (o0 > t1) + (o1 > t1) + (o2 > t1) + (o3 > t1);
          r2 += (o0 > t2) + (o1 > t2) + (o2 > t2) + (o3 > t2);
          r3 += (o0 > t3) + (o1 > t3) + (o2 > t3) + (o3 > t3);
        }
        int cut = (t3 != 0ull) ? (r3 + 1) : 0x7FFFFFFF;
        int nc = (t0 != 0ull) + (t1 != 0ull) + (t2 != 0ull) + (t3 != 0ull);
        for (int off = 32; off > 0; off >>= 1) {
          int oc = __shfl_xor(cut, off);
          cut = (oc < cut) ? oc : cut;
          nc += __shfl_xor(nc, off);
        }
        const int Lf = (cut < DEPTH_) ? cut : DEPTH_;
        const int zstart = (Lf < nc) ? Lf : nc;
        if (t0 != 0ull && r0 < Lf) {
          s_tlkey[col][r0] = t0;
          s_tlrow[col][r0] = (unsigned short)(4095 - (int)((t0 >> 12) & 0xFFF));
        }
        if (t1 != 0ull && r1 < Lf) {
          s_tlkey[col][r1] = t1;
          s_tlrow[col][r1] = (unsigned short)(4095 - (int)((t1 >> 12) & 0xFFF));
        }
        if (t2 != 0ull && r2 < Lf) {
          s_tlkey[col][r2] = t2;
          s_tlrow[col][r2] = (unsigned short)(4095 - (int)((t2 >> 12) & 0xFFF));
        }
        if (t3 != 0ull && r3 < Lf) {
          s_tlkey[col][r3] = t3;
          s_tlrow[col][r3] = (unsigned short)(4095 - (int)((t3 >> 12) & 0xFFF));
        }
        for (int o = lane; o < DEPTH_; o += 64)
          if (o >= zstart) { s_tlkey[col][o] = 0ull; s_tlrow[col][o] = 0xFFFF; }
        __builtin_amdgcn_wave_barrier();
        ull newhead = s_tlkey[col][0];
        if (lane == src) {
          ull nk = (newhead << 8) | (ull)(255 - col);
          if (slot == 0) { key0 = nk; ptr0 = 1; }
          else if (slot == 1) { key1 = nk; ptr1 = 1; }
          else if (slot == 2) { key2 = nk; ptr2 = 1; }
          else { key3 = nk; ptr3 = 1; }
          need &= ~(1 << slot);
        }
        __builtin_amdgcn_wave_barrier();
      }
      step += nacc;
    }
  }
  __syncthreads();

  // ---- epilogue: CIoU + CE over matches, BCE objectness over all K ----
  const int cnt = s_cnt;
  float lbox = 0.f, lcls = 0.f;
  for (int i = tid; i < cnt; i += 1024) {
    int p = s_mp[i], g = s_mg[i];
    float4 pb = p4[p];
    float4 gb = make_float4(s_gx[g], s_gy[g], s_gz[g], s_gw[g]);
    lbox += ciou_loss(pb, gb);
    int label = gt_labels[(size_t)b * G_ + g];
    const float* lg = cls_logits + ((size_t)b * K_ + p) * C_;
    float m = -1e30f;
    for (int cc = 0; cc < C_; ++cc) m = fmaxf(m, lg[cc]);
    float s = 0.f;
    for (int cc = 0; cc < C_; ++cc) s += expf(lg[cc] - m);
    lcls += (m + logf(s)) - lg[label];
  }
  float obj = 0.f;
  const float* ol = obj_logits + (size_t)b * K_;
  for (int k = tid; k < K_; k += 1024) {
    float x = ol[k];
    float sp = fmaxf(x, 0.f) + log1pf(expf(-fabsf(x)));  // softplus(x)
    if (s_rowused[k]) sp -= x;                           // - t*x
    obj += sp;
  }
  lbox = block_sum(lbox, s_red);
  lcls = block_sum(lcls, s_red);
  obj = block_sum(obj, s_red);
  if (tid == 0) {
    float* partials = (float*)(ws + WS_PART);
    float n = (float)cnt;
    float denom = fmaxf(n, 1.f);
    partials[b * 4 + 0] = lbox / denom;
    partials[b * 4 + 1] = lcls / denom;
    partials[b * 4 + 2] = obj;
    partials[b * 4 + 3] = (n > 0.f) ? 1.f : 0.f;
  }
}

__global__ void kfinal(const char* __restrict__ ws, float* __restrict__ out) {
  int b = threadIdx.x;  // 64 threads, one wave
  const float* partials = (const float*)(ws + WS_PART);
  float lb = partials[b * 4 + 0], lc = partials[b * 4 + 1];
  float ob = partials[b * 4 + 2], hf = partials[b * 4 + 3];
  float sb = lb * hf, sc = lc * hf, sh = hf, so = ob;
  for (int off = 32; off > 0; off >>= 1) {
    sb += __shfl_xor(sb, off);
    sc += __shfl_xor(sc, off);
    sh += __shfl_xor(sh, off);
    so += __shfl_xor(so, off);
  }
  if (b == 0) {
    float nb = fmaxf(sh, 1.f);
    float box = sb / nb, cls = sc / nb;
    float obj = so / (float)(B_ * K_);
    out[0] = 5.f * box + cls + obj;
    out[1] = box;
    out[2] = cls;
    out[3] = obj;
  }
}

extern "C" void kernel_launch(void* const* d_in, const int* in_sizes, int n_in,
                              void* d_out, int out_size, void* d_ws, size_t ws_size,
                              hipStream_t stream) {
  const float* pred_boxes = (const float*)d_in[0];
  const float* obj_logits = (const float*)d_in[1];
  const float* cls_logits = (const float*)d_in[2];
  const float* gt_boxes = (const float*)d_in[3];
  const int* gt_labels = (const int*)d_in[4];
  const void* gt_mask = d_in[5];
  float* out = (float*)d_out;
  char* ws = (char*)d_ws;

  hipLaunchKernelGGL(kdetect, dim3(1), dim3(64), 0, stream,
                     (const unsigned char*)gt_mask, (int*)(ws + WS_FLAG));
  hipLaunchKernelGGL(kinit, dim3(400), dim3(1024), 0, stream,
                     pred_boxes, gt_boxes, gt_mask, ws);
  hipLaunchKernelGGL(kmerged, dim3(B_), dim3(1024), 0, stream,
                     pred_boxes, obj_logits, cls_logits, gt_boxes, gt_labels,
                     gt_mask, ws);
  hipLaunchKernelGGL(kfinal, dim3(1), dim3(64), 0, stream, ws, out);
}

// Round 16
// 273.313 us; speedup vs baseline: 1.0939x; 1.0727x over previous
//
#include <hip/hip_runtime.h>
#include <math.h>

#define B_ 64
#define K_ 4000
#define G_ 200
#define C_ 91
#define EPS_ 1e-9f
#define NW_ 16
#define DEPTH_ 32
typedef unsigned long long ull;

// ws layout (byte offsets); total use ~3.4 MB
#define WS_FLAG 0
#define WS_PART 256   // 64*4 f32
#define WS_TOP 65536  // 64*200*32 ull = 3.28 MB (exact top-L lists, L<=32)

// list key: (iou_bits << 12) | (4095 - p)   — iou desc, then p asc; always > 0
// full key: (list << 8) | (255 - g)         — iou desc, p asc, g asc == argmax flat order
__device__ __forceinline__ float box_area(float4 a) {
#pragma clang fp contract(off)
  return fmaxf(a.z - a.x, 0.f) * fmaxf(a.w - a.y, 0.f);
}

// IoU; contract(off) => bit-identical across init and rescan
__device__ __forceinline__ float iou_ab(float4 a, float aA, float4 b, float aB) {
#pragma clang fp contract(off)
  float tlx = fmaxf(a.x, b.x), tly = fmaxf(a.y, b.y);
  float brx = fminf(a.z, b.z), bry = fminf(a.w, b.w);
  float w = fmaxf(brx - tlx, 0.f), h = fmaxf(bry - tly, 0.f);
  float inter = w * h;
  float uni = fmaxf(aA + aB - inter, EPS_);
  return inter / uni;
}

__device__ __forceinline__ float ciou_loss(float4 p, float4 g) {
  float tlx = fmaxf(p.x, g.x), tly = fmaxf(p.y, g.y);
  float brx = fminf(p.z, g.z), bry = fminf(p.w, g.w);
  float w = fmaxf(brx - tlx, 0.f), h = fmaxf(bry - tly, 0.f);
  float inter = w * h;
  float areaP = fmaxf(p.z - p.x, 0.f) * fmaxf(p.w - p.y, 0.f);
  float areaG = fmaxf(g.z - g.x, 0.f) * fmaxf(g.w - g.y, 0.f);
  float iou = inter / fmaxf(areaP + areaG - inter, EPS_);
  float px = (p.x + p.z) * 0.5f, py = (p.y + p.w) * 0.5f;
  float tx = (g.x + g.z) * 0.5f, ty = (g.y + g.w) * 0.5f;
  float rho2 = (px - tx) * (px - tx) + (py - ty) * (py - ty);
  float ex = fmaxf(p.z, g.z) - fminf(p.x, g.x);
  float ey = fmaxf(p.w, g.w) - fminf(p.y, g.y);
  float c2 = fmaxf(ex * ex + ey * ey, EPS_);
  float pw = fmaxf(p.z - p.x, EPS_), ph = fmaxf(p.w - p.y, EPS_);
  float tw = fmaxf(g.z - g.x, EPS_), th = fmaxf(g.w - g.y, EPS_);
  float dat = atanf(tw / th) - atanf(pw / ph);
  float v = (4.0f / (float)(M_PI * M_PI)) * dat * dat;
  float alpha = v / ((1.f - iou) + v + EPS_);
  return 1.f - (iou - rho2 / c2 - alpha * v);
}

// gt_mask layout detector (int8 bool vs 4-byte elems) — unchanged (passed R1-R15)
__global__ void kdetect(const unsigned char* m8, int* flag) {
  int b = threadIdx.x;
  int ok = 1;
  const unsigned char* r = m8 + b * G_;
  if (r[0] != 1) ok = 0;
  int seen0 = 0;
  for (int g = 0; g < G_; ++g) {
    unsigned char c = r[g];
    if (c > 1) { ok = 0; break; }
    if (c == 0) seen0 = 1;
    else if (seen0) { ok = 0; break; }
  }
  int all = __all(ok);
  if (b == 0) *flag = all ? 1 : 0;
}

__device__ __forceinline__ float block_sum(float v, float* s_red) {
  for (int off = 32; off > 0; off >>= 1) v += __shfl_xor(v, off);
  int lane = threadIdx.x & 63, wid = threadIdx.x >> 6;
  if (lane == 0) s_red[wid] = v;
  __syncthreads();
  float r = 0.f;
  if (wid == 0) {
    float t = (lane < NW_) ? s_red[lane] : 0.f;
    for (int off = 32; off > 0; off >>= 1) t += __shfl_xor(t, off);
    r = t;
  }
  __syncthreads();
  return r;  // valid at tid 0
}

// one butterfly stage of wave top-8 reduce: bitonic-merge own sorted-desc
// 8-list with partner's, keep top 8 (t_i = max(v_i, w_{7-i}), clean 4/2/1).
// 6 stages converge all lanes to the identical exact global top-8.
__device__ __forceinline__ void merge8_stage(ull* v, int off) {
  ull w0 = __shfl_xor(v[0], off), w1 = __shfl_xor(v[1], off);
  ull w2 = __shfl_xor(v[2], off), w3 = __shfl_xor(v[3], off);
  ull w4 = __shfl_xor(v[4], off), w5 = __shfl_xor(v[5], off);
  ull w6 = __shfl_xor(v[6], off), w7 = __shfl_xor(v[7], off);
  ull t0 = v[0] > w7 ? v[0] : w7;
  ull t1 = v[1] > w6 ? v[1] : w6;
  ull t2 = v[2] > w5 ? v[2] : w5;
  ull t3 = v[3] > w4 ? v[3] : w4;
  ull t4 = v[4] > w3 ? v[4] : w3;
  ull t5 = v[5] > w2 ? v[5] : w2;
  ull t6 = v[6] > w1 ? v[6] : w1;
  ull t7 = v[7] > w0 ? v[7] : w0;
  ull x;
  // bitonic clean, desc: distances 4, 2, 1
  if (t4 > t0) { x = t0; t0 = t4; t4 = x; }
  if (t5 > t1) { x = t1; t1 = t5; t5 = x; }
  if (t6 > t2) { x = t2; t2 = t6; t6 = x; }
  if (t7 > t3) { x = t3; t3 = t7; t7 = x; }
  if (t2 > t0) { x = t0; t0 = t2; t2 = x; }
  if (t3 > t1) { x = t1; t1 = t3; t3 = x; }
  if (t6 > t4) { x = t4; t4 = t6; t6 = x; }
  if (t7 > t5) { x = t5; t5 = t7; t7 = x; }
  if (t1 > t0) { x = t0; t0 = t1; t1 = x; }
  if (t3 > t2) { x = t2; t2 = t3; t3 = x; }
  if (t5 > t4) { x = t4; t4 = t5; t5 = x; }
  if (t7 > t6) { x = t6; t6 = t7; t7 = x; }
  v[0] = t0; v[1] = t1; v[2] = t2; v[3] = t3;
  v[4] = t4; v[5] = t5; v[6] = t6; v[7] = t7;
}

// register-resident sorted-desc top-4 insert (cheap chain; exec-mask friendly)
#define TOP4_INS(key, t0, t1, t2, t3)                   \
  if ((key) > t3) {                                     \
    t3 = (key);                                         \
    ull tmp_;                                           \
    if (t3 > t2) { tmp_ = t2; t2 = t3; t3 = tmp_; }     \
    if (t2 > t1) { tmp_ = t1; t1 = t2; t2 = tmp_; }     \
    if (t1 > t0) { tmp_ = t0; t0 = t1; t1 = tmp_; }     \
  }

// rank-sort extraction (same written prefix as the R8-R12 drain-stop pops)
__device__ __forceinline__ void rank_extract(ull t0, ull t1, ull t2, ull t3,
                                             ull* dst, int lane) {
  int r0 = 0, r1 = 0, r2 = 0, r3 = 0;
  for (int i = 0; i < 64; ++i) {
    ull o0 = __shfl(t0, i), o1 = __shfl(t1, i);
    ull o2 = __shfl(t2, i), o3 = __shfl(t3, i);
    r0 += (o0 > t0) + (o1 > t0) + (o2 > t0) + (o3 > t0);
    r1 += (o0 > t1) + (o1 > t1) + (o2 > t1) + (o3 > t1);
    r2 += (o0 > t2) + (o1 > t2) + (o2 > t2) + (o3 > t2);
    r3 += (o0 > t3) + (o1 > t3) + (o2 > t3) + (o3 > t3);
  }
  int cut = (t3 != 0ull) ? (r3 + 1) : 0x7FFFFFFF;
  int nc = (t0 != 0ull) + (t1 != 0ull) + (t2 != 0ull) + (t3 != 0ull);
  for (int off = 32; off > 0; off >>= 1) {
    int oc = __shfl_xor(cut, off);
    cut = (oc < cut) ? oc : cut;
    nc += __shfl_xor(nc, off);
  }
  const int Lf = (cut < DEPTH_) ? cut : DEPTH_;
  const int zstart = (Lf < nc) ? Lf : nc;
  if (t0 != 0ull && r0 < Lf) dst[r0] = t0;
  if (t1 != 0ull && r1 < Lf) dst[r1] = t1;
  if (t2 != 0ull && r2 < Lf) dst[r2] = t2;
  if (t3 != 0ull && r3 < Lf) dst[r3] = t3;
  for (int o = lane; o < DEPTH_; o += 64)
    if (o >= zstart) dst[o] = 0ull;
}

// ---- phase 1: wave-per-column exact top-L lists; fused 2-col scan ----
// (R13/R14 proven form, ~128us: LDS-staged pred, octant blocks.)
__global__ __launch_bounds__(1024) void kinit(const float* __restrict__ pred_boxes,
                                              const float* __restrict__ gt_boxes,
                                              const void* __restrict__ gt_mask,
                                              char* __restrict__ ws) {
  __shared__ float4 s_p[K_];  // 64 KB staged pred boxes
  const int blk = blockIdx.x;
  const int b = blk >> 3, oct = blk & 7;
  const int tid = threadIdx.x, lane = tid & 63, wid = tid >> 6;
  const int msk8 = *(const int*)(ws + WS_FLAG);
  const float4* p4 = (const float4*)pred_boxes + (size_t)b * K_;
  const float4* g4 = (const float4*)gt_boxes + (size_t)b * G_;

  for (int i = tid; i < K_; i += 1024) s_p[i] = p4[i];
  __syncthreads();

  const int base = oct * 25;
  const int colA = base + wid;
  const int colB = base + 16 + wid;
  const bool hasB = (wid < 9);
  ull* wtop = (ull*)(ws + WS_TOP);

  int vA, vB = 0;
  if (msk8) vA = ((const unsigned char*)gt_mask)[(size_t)b * G_ + colA] != 0;
  else      vA = ((const int*)gt_mask)[(size_t)b * G_ + colA] != 0;
  if (hasB) {
    if (msk8) vB = ((const unsigned char*)gt_mask)[(size_t)b * G_ + colB] != 0;
    else      vB = ((const int*)gt_mask)[(size_t)b * G_ + colB] != 0;
  }

  float4 gbA, gbB;
  float gAA = 0.f, gAB = 0.f;
  if (vA) { gbA = g4[colA]; gAA = box_area(gbA); }
  if (vB) { gbB = g4[colB]; gAB = box_area(gbB); }

  ull a0 = 0, a1 = 0, a2 = 0, a3 = 0;
  ull b0 = 0, b1 = 0, b2 = 0, b3 = 0;
  if (vA | vB) {
#pragma unroll 2
    for (int k = lane; k < K_; k += 64) {
      float4 pb = s_p[k];
      float ar = box_area(pb);
      if (vA) {
        float iou = iou_ab(pb, ar, gbA, gAA);
        ull e = ((ull)__float_as_uint(iou) << 12) | (ull)(4095 - k);
        TOP4_INS(e, a0, a1, a2, a3);
      }
      if (vB) {
        float iou = iou_ab(pb, ar, gbB, gAB);
        ull e = ((ull)__float_as_uint(iou) << 12) | (ull)(4095 - k);
        TOP4_INS(e, b0, b1, b2, b3);
      }
    }
  }
  {
    ull* dstA = wtop + ((size_t)b * G_ + colA) * DEPTH_;
    if (vA) rank_extract(a0, a1, a2, a3, dstA, lane);
    else    for (int o = lane; o < DEPTH_; o += 64) dstA[o] = 0ull;
  }
  if (hasB) {
    ull* dstB = wtop + ((size_t)b * G_ + colB) * DEPTH_;
    if (vB) rank_extract(b0, b1, b2, b3, dstB, lane);
    else    for (int o = lane; o < DEPTH_; o += 64) dstB[o] = 0ull;
  }
}

// ---- phase 2+3 fused: greedy matching (wave 0, OCT-pop) + epilogue ----
__global__ __launch_bounds__(1024) void kmerged(
    const float* __restrict__ pred_boxes, const float* __restrict__ obj_logits,
    const float* __restrict__ cls_logits, const float* __restrict__ gt_boxes,
    const int* __restrict__ gt_labels, const void* __restrict__ gt_mask,
    char* __restrict__ ws) {
  __shared__ float s_gx[G_], s_gy[G_], s_gz[G_], s_gw[G_], s_garea[G_];
  __shared__ unsigned char s_valid[G_];
  __shared__ unsigned char s_rowused[4096];
  __shared__ ull s_tlkey[G_][DEPTH_ + 1];            // stride 33: bank-spread
  __shared__ unsigned short s_tlrow[G_][DEPTH_ + 1]; // decoded rows for walks
  __shared__ int s_mp[G_];
  __shared__ unsigned short s_mg[G_];
  __shared__ int s_cnt;
  __shared__ float s_red[NW_];
  const int b = blockIdx.x;
  const int tid = threadIdx.x, lane = tid & 63, wid = tid >> 6;
  const int msk8 = *(const int*)(ws + WS_FLAG);
  const float4* p4 = (const float4*)pred_boxes + (size_t)b * K_;
  const float4* g4 = (const float4*)gt_boxes + (size_t)b * G_;
  const ull* wtop = (const ull*)(ws + WS_TOP);

  for (int g = tid; g < G_; g += 1024) {
    float4 gb = g4[g];
    s_gx[g] = gb.x; s_gy[g] = gb.y; s_gz[g] = gb.z; s_gw[g] = gb.w;
    s_garea[g] = box_area(gb);
    int v;
    if (msk8) v = ((const unsigned char*)gt_mask)[(size_t)b * G_ + g] != 0;
    else      v = ((const int*)gt_mask)[(size_t)b * G_ + g] != 0;
    s_valid[g] = (unsigned char)v;
  }
  for (int k = tid; k < 4096; k += 1024) s_rowused[k] = 0;
  __syncthreads();
  for (int i = tid; i < G_ * DEPTH_; i += 1024) {
    int col = i >> 5, o = i & 31;
    ull v = s_valid[col] ? wtop[(size_t)b * G_ * DEPTH_ + i] : 0ull;
    s_tlkey[col][o] = v;
    s_tlrow[col][o] = v ? (unsigned short)(4095 - (int)((v >> 12) & 0xFFF))
                        : (unsigned short)0xFFFF;
  }
  __syncthreads();

  if (wid == 0) {
    ull key0 = 0, key1 = 0, key2 = 0, key3 = 0;
    int ptr0 = DEPTH_, ptr1 = DEPTH_, ptr2 = DEPTH_, ptr3 = DEPTH_;
    int cloc = 0;
#define SLOTINIT(S)                                                        \
    { int col = S * 64 + lane;                                             \
      if (col < G_) {                                                      \
        ull h_ = s_tlkey[col][0];                                          \
        if (h_ != 0ull) {                                                  \
          key##S = (h_ << 8) | (ull)(255 - col); ptr##S = 1; ++cloc; } } }
    SLOTINIT(0) SLOTINIT(1) SLOTINIT(2) SLOTINIT(3)
#undef SLOTINIT
    for (int off = 32; off > 0; off >>= 1) cloc += __shfl_xor(cloc, off);
    const int cnt = cloc;
    if (lane == 0) s_cnt = cnt;

    for (int step = 0; step < cnt;) {
      // lane-local sorted-desc 4-list of slot keys + 4 zeros = sorted 8-list
      ull v[8];
      {
        ull q0 = key0, q1 = key1, q2 = key2, q3 = key3, x;
        if (q1 > q0) { x = q0; q0 = q1; q1 = x; }
        if (q3 > q2) { x = q2; q2 = q3; q3 = x; }
        if (q2 > q0) { x = q0; q0 = q2; q2 = x; }
        if (q3 > q1) { x = q1; q1 = q3; q3 = x; }
        if (q2 > q1) { x = q1; q1 = q2; q2 = x; }
        v[0] = q0; v[1] = q1; v[2] = q2; v[3] = q3;
        v[4] = 0; v[5] = 0; v[6] = 0; v[7] = 0;
      }
      // wave top-8 reduce (exact): 6 bitonic-merge butterfly stages
      merge8_stage(v, 32);
      merge8_stage(v, 16);
      merge8_stage(v, 8);
      merge8_stage(v, 4);
      merge8_stage(v, 2);
      merge8_stage(v, 1);
      int P[8], Gc[8];
#pragma unroll
      for (int i = 0; i < 8; ++i) {
        P[i] = 4095 - (int)((v[i] >> 8) & 0xFFF);
        Gc[i] = 255 - (int)(v[i] & 0xFF);
      }
      // accept maximal prefix with pairwise-distinct rows (exactness: demotions
      // from pop i only touch cols whose best row == p_i; distinct row of
      // candidate i+1 => its key is still the exact global max after pops 1..i)
      const int lim = cnt - step;
      bool okp = true;
      int nacc = 0;
      int gacc[8], pacc[8];
#pragma unroll
      for (int i = 0; i < 8; ++i) {
        bool d = (v[i] != 0ull) && (lim > i);
#pragma unroll
        for (int j = 0; j < 8; ++j)
          if (j < i) d = d && (P[i] != P[j]);
        okp = okp && d;
        gacc[i] = okp ? Gc[i] : -1;
        pacc[i] = okp ? P[i] : -1;
        if (okp) ++nacc;
      }
      if (lane == 0) {
#pragma unroll
        for (int i = 0; i < 8; ++i)
          if (i < nacc) {
            s_mp[step + i] = P[i];
            s_mg[step + i] = (unsigned short)Gc[i];
            s_rowused[P[i]] = 1;
          }
      }
      __builtin_amdgcn_wave_barrier();
      int need = 0;
#define DEMOTE(S)                                                           \
      { int col = S * 64 + lane; ull kk = key##S;                           \
        if (kk != 0ull) {                                                   \
          bool kill = false;                                                \
          _Pragma("unroll") for (int i = 0; i < 8; ++i)                     \
            kill |= (col == gacc[i]);                                       \
          if (kill) { key##S = 0ull; }                                      \
          else {                                                            \
            int krow = 4095 - (int)((kk >> 8) & 0xFFF);                     \
            bool stale = false;                                             \
            _Pragma("unroll") for (int i = 0; i < 8; ++i)                   \
              stale |= (krow == pacc[i]);                                   \
            if (stale) {                                                    \
              ull nk = 0ull; int np = ptr##S;                               \
              while (np < DEPTH_) {                                         \
                int r_ = s_tlrow[col][np];                                  \
                if (r_ == 0xFFFF) { np = DEPTH_; break; }                   \
                if (!s_rowused[r_]) {                                       \
                  nk = (s_tlkey[col][np] << 8) | (ull)(255 - col);          \
                  ++np; break;                                              \
                }                                                           \
                ++np;                                                       \
              }                                                             \
              ptr##S = np; key##S = nk;                                     \
              if (nk == 0ull) need |= (1 << S); } } } }
      DEMOTE(0) DEMOTE(1) DEMOTE(2) DEMOTE(3)
#undef DEMOTE
      // exact fallback: full rescan over unused rows; rank-sort refill
      while (__any(need)) {
        unsigned long long bal = __ballot(need != 0);
        int src = (int)__builtin_ctzll(bal);
        int myslot = need ? __builtin_ctz(need) : 0;
        int slot = __shfl(myslot, src);
        int col = slot * 64 + src;
        float4 gb = make_float4(s_gx[col], s_gy[col], s_gz[col], s_gw[col]);
        float gA2 = s_garea[col];
        ull t0 = 0, t1 = 0, t2 = 0, t3 = 0;
#pragma unroll 2
        for (int k = lane; k < K_; k += 64) {
          if (!s_rowused[k]) {
            float4 pb = p4[k];
            float iou = iou_ab(pb, box_area(pb), gb, gA2);
            ull e = ((ull)__float_as_uint(iou) << 12) | (ull)(4095 - k);
            TOP4_INS(e, t0, t1, t2, t3);
          }
        }
        int r0 = 0, r1 = 0, r2 = 0, r3 = 0;
        for (int i = 0; i < 64; ++i) {
          ull o0 = __shfl(t0, i), o1 = __shfl(t1, i);
          ull o2 = __shfl(t2, i), o3 = __shfl(t3, i);
          r0 += (o0 > t0) + (o1 > t0) + (o2 > t0) + (o3 > t0);
          r1 += (o0 > t1) + (o1 > t1) + (o2 > t1) + (o3 > t1);
          r2 += (o0 > t2) + (o1 > t2) + (o2 > t2) + (o3 > t2);
          r3 += (o0 > t3) + (o1 > t3) + (o2 > t3) + (o3 > t3);
        }
        int cut = (t3 != 0ull) ? (r3 + 1) : 0x7FFFFFFF;
        int nc = (t0 != 0ull) + (t1 != 0ull) + (t2 != 0ull) + (t3 != 0ull);
        for (int off = 32; off > 0; off >>= 1) {
          int oc = __shfl_xor(cut, off);
          cut = (oc < cut) ? oc : cut;
          nc += __shfl_xor(nc, off);
        }
        const int Lf = (cut < DEPTH_) ? cut : DEPTH_;
        const int zstart = (Lf < nc) ? Lf : nc;
        if (t0 != 0ull && r0 < Lf) {
          s_tlkey[col][r0] = t0;
          s_tlrow[col][r0] = (unsigned short)(4095 - (int)((t0 >> 12) & 0xFFF));
        }
        if (t1 != 0ull && r1 < Lf) {
          s_tlkey[col][r1] = t1;
          s_tlrow[col][r1] = (unsigned short)(4095 - (int)((t1 >> 12) & 0xFFF));
        }
        if (t2 != 0ull && r2 < Lf) {
          s_tlkey[col][r2] = t2;
          s_tlrow[col][r2] = (unsigned short)(4095 - (int)((t2 >> 12) & 0xFFF));
        }
        if (t3 != 0ull && r3 < Lf) {
          s_tlkey[col][r3] = t3;
          s_tlrow[col][r3] = (unsigned short)(4095 - (int)((t3 >> 12) & 0xFFF));
        }
        for (int o = lane; o < DEPTH_; o += 64)
          if (o >= zstart) { s_tlkey[col][o] = 0ull; s_tlrow[col][o] = 0xFFFF; }
        __builtin_amdgcn_wave_barrier();
        ull newhead = s_tlkey[col][0];
        if (lane == src) {
          ull nk = (newhead << 8) | (ull)(255 - col);
          if (slot == 0) { key0 = nk; ptr0 = 1; }
          else if (slot == 1) { key1 = nk; ptr1 = 1; }
          else if (slot == 2) { key2 = nk; ptr2 = 1; }
          else { key3 = nk; ptr3 = 1; }
          need &= ~(1 << slot);
        }
        __builtin_amdgcn_wave_barrier();
      }
      step += nacc;
    }
  }
  __syncthreads();

  // ---- epilogue: CIoU + CE over matches, BCE objectness over all K ----
  const int cnt = s_cnt;
  float lbox = 0.f, lcls = 0.f;
  for (int i = tid; i < cnt; i += 1024) {
    int p = s_mp[i], g = s_mg[i];
    float4 pb = p4[p];
    float4 gb = make_float4(s_gx[g], s_gy[g], s_gz[g], s_gw[g]);
    lbox += ciou_loss(pb, gb);
    int label = gt_labels[(size_t)b * G_ + g];
    const float* lg = cls_logits + ((size_t)b * K_ + p) * C_;
    float m = -1e30f;
    for (int cc = 0; cc < C_; ++cc) m = fmaxf(m, lg[cc]);
    float s = 0.f;
    for (int cc = 0; cc < C_; ++cc) s += expf(lg[cc] - m);
    lcls += (m + logf(s)) - lg[label];
  }
  float obj = 0.f;
  const float* ol = obj_logits + (size_t)b * K_;
  for (int k = tid; k < K_; k += 1024) {
    float x = ol[k];
    float sp = fmaxf(x, 0.f) + log1pf(expf(-fabsf(x)));  // softplus(x)
    if (s_rowused[k]) sp -= x;                           // - t*x
    obj += sp;
  }
  lbox = block_sum(lbox, s_red);
  lcls = block_sum(lcls, s_red);
  obj = block_sum(obj, s_red);
  if (tid == 0) {
    float* partials = (float*)(ws + WS_PART);
    float n = (float)cnt;
    float denom = fmaxf(n, 1.f);
    partials[b * 4 + 0] = lbox / denom;
    partials[b * 4 + 1] = lcls / denom;
    partials[b * 4 + 2] = obj;
    partials[b * 4 + 3] = (n > 0.f) ? 1.f : 0.f;
  }
}

__global__ void kfinal(const char* __restrict__ ws, float* __restrict__ out) {
  int b = threadIdx.x;  // 64 threads, one wave
  const float* partials = (const float*)(ws + WS_PART);
  float lb = partials[b * 4 + 0], lc = partials[b * 4 + 1];
  float ob = partials[b * 4 + 2], hf = partials[b * 4 + 3];
  float sb = lb * hf, sc = lc * hf, sh = hf, so = ob;
  for (int off = 32; off > 0; off >>= 1) {
    sb += __shfl_xor(sb, off);
    sc += __shfl_xor(sc, off);
    sh += __shfl_xor(sh, off);
    so += __shfl_xor(so, off);
  }
  if (b == 0) {
    float nb = fmaxf(sh, 1.f);
    float box = sb / nb, cls = sc / nb;
    float obj = so / (float)(B_ * K_);
    out[0] = 5.f * box + cls + obj;
    out[1] = box;
    out[2] = cls;
    out[3] = obj;
  }
}

extern "C" void kernel_launch(void* const* d_in, const int* in_sizes, int n_in,
                              void* d_out, int out_size, void* d_ws, size_t ws_size,
                              hipStream_t stream) {
  const float* pred_boxes = (const float*)d_in[0];
  const float* obj_logits = (const float*)d_in[1];
  const float* cls_logits = (const float*)d_in[2];
  const float* gt_boxes = (const float*)d_in[3];
  const int* gt_labels = (const int*)d_in[4];
  const void* gt_mask = d_in[5];
  float* out = (float*)d_out;
  char* ws = (char*)d_ws;

  hipLaunchKernelGGL(kdetect, dim3(1), dim3(64), 0, stream,
                     (const unsigned char*)gt_mask, (int*)(ws + WS_FLAG));
  hipLaunchKernelGGL(kinit, dim3(B_ * 8), dim3(1024), 0, stream,
                     pred_boxes, gt_boxes, gt_mask, ws);
  hipLaunchKernelGGL(kmerged, dim3(B_), dim3(1024), 0, stream,
                     pred_boxes, obj_logits, cls_logits, gt_boxes, gt_labels,
                     gt_mask, ws);
  hipLaunchKernelGGL(kfinal, dim3(1), dim3(64), 0, stream, ws, out);
}

// Round 17
// 252.868 us; speedup vs baseline: 1.1823x; 1.0809x over previous
//
#include <hip/hip_runtime.h>
#include <math.h>

#define B_ 64
#define K_ 4000
#define G_ 200
#define C_ 91
#define EPS_ 1e-9f
#define NW_ 16
#define DEPTH_ 32
typedef unsigned long long ull;

// ws layout (byte offsets); total use ~3.6 MB
#define WS_FLAG 0
#define WS_PART 256        // 64*4 f32
#define WS_TOP 327680      // 64*200*32 ull = 3.28 MB (exact top-L lists, L<=32)

// list key: (iou_bits << 12) | (4095 - p)   — iou desc, then p asc; always > 0
// full key: (list << 8) | (255 - g)         — iou desc, p asc, g asc == argmax flat order
__device__ __forceinline__ float box_area(float4 a) {
#pragma clang fp contract(off)
  return fmaxf(a.z - a.x, 0.f) * fmaxf(a.w - a.y, 0.f);
}

// IoU; contract(off) => bit-identical across init and rescan
__device__ __forceinline__ float iou_ab(float4 a, float aA, float4 b, float aB) {
#pragma clang fp contract(off)
  float tlx = fmaxf(a.x, b.x), tly = fmaxf(a.y, b.y);
  float brx = fminf(a.z, b.z), bry = fminf(a.w, b.w);
  float w = fmaxf(brx - tlx, 0.f), h = fmaxf(bry - tly, 0.f);
  float inter = w * h;
  float uni = fmaxf(aA + aB - inter, EPS_);
  return inter / uni;
}

__device__ __forceinline__ float ciou_loss(float4 p, float4 g) {
  float tlx = fmaxf(p.x, g.x), tly = fmaxf(p.y, g.y);
  float brx = fminf(p.z, g.z), bry = fminf(p.w, g.w);
  float w = fmaxf(brx - tlx, 0.f), h = fmaxf(bry - tly, 0.f);
  float inter = w * h;
  float areaP = fmaxf(p.z - p.x, 0.f) * fmaxf(p.w - p.y, 0.f);
  float areaG = fmaxf(g.z - g.x, 0.f) * fmaxf(g.w - g.y, 0.f);
  float iou = inter / fmaxf(areaP + areaG - inter, EPS_);
  float px = (p.x + p.z) * 0.5f, py = (p.y + p.w) * 0.5f;
  float tx = (g.x + g.z) * 0.5f, ty = (g.y + g.w) * 0.5f;
  float rho2 = (px - tx) * (px - tx) + (py - ty) * (py - ty);
  float ex = fmaxf(p.z, g.z) - fminf(p.x, g.x);
  float ey = fmaxf(p.w, g.w) - fminf(p.y, g.y);
  float c2 = fmaxf(ex * ex + ey * ey, EPS_);
  float pw = fmaxf(p.z - p.x, EPS_), ph = fmaxf(p.w - p.y, EPS_);
  float tw = fmaxf(g.z - g.x, EPS_), th = fmaxf(g.w - g.y, EPS_);
  float dat = atanf(tw / th) - atanf(pw / ph);
  float v = (4.0f / (float)(M_PI * M_PI)) * dat * dat;
  float alpha = v / ((1.f - iou) + v + EPS_);
  return 1.f - (iou - rho2 / c2 - alpha * v);
}

// gt_mask layout detector (int8 bool vs 4-byte elems) — unchanged (passed R1-R16)
__global__ void kdetect(const unsigned char* m8, int* flag) {
  int b = threadIdx.x;
  int ok = 1;
  const unsigned char* r = m8 + b * G_;
  if (r[0] != 1) ok = 0;
  int seen0 = 0;
  for (int g = 0; g < G_; ++g) {
    unsigned char c = r[g];
    if (c > 1) { ok = 0; break; }
    if (c == 0) seen0 = 1;
    else if (seen0) { ok = 0; break; }
  }
  int all = __all(ok);
  if (b == 0) *flag = all ? 1 : 0;
}

__device__ __forceinline__ float block_sum(float v, float* s_red) {
  for (int off = 32; off > 0; off >>= 1) v += __shfl_xor(v, off);
  int lane = threadIdx.x & 63, wid = threadIdx.x >> 6;
  if (lane == 0) s_red[wid] = v;
  __syncthreads();
  float r = 0.f;
  if (wid == 0) {
    float t = (lane < NW_) ? s_red[lane] : 0.f;
    for (int off = 32; off > 0; off >>= 1) t += __shfl_xor(t, off);
    r = t;
  }
  __syncthreads();
  return r;  // valid at tid 0
}

__device__ __forceinline__ ull wave_maxkey(ull k) {
  for (int off = 32; off > 0; off >>= 1) {
    ull o = __shfl_xor(k, off);
    if (o > k) k = o;
  }
  return k;
}

// one butterfly stage of wave top-4 reduce: merge own sorted-desc 4-list with
// partner's (bitonic merge, keep top 4, re-sorted desc). All lanes converge
// to the identical exact global top-4 after 6 stages.
__device__ __forceinline__ void merge4_stage(ull& v0, ull& v1, ull& v2, ull& v3,
                                             int off) {
  ull w0 = __shfl_xor(v0, off), w1 = __shfl_xor(v1, off);
  ull w2 = __shfl_xor(v2, off), w3 = __shfl_xor(v3, off);
  ull t0 = v0 > w3 ? v0 : w3;
  ull t1 = v1 > w2 ? v1 : w2;
  ull t2 = v2 > w1 ? v2 : w1;
  ull t3 = v3 > w0 ? v3 : w0;
  ull x;
  if (t2 > t0) { x = t0; t0 = t2; t2 = x; }
  if (t3 > t1) { x = t1; t1 = t3; t3 = x; }
  if (t1 > t0) { x = t0; t0 = t1; t1 = x; }
  if (t3 > t2) { x = t2; t2 = t3; t3 = x; }
  v0 = t0; v1 = t1; v2 = t2; v3 = t3;
}

// register-resident sorted-desc top-4 insert (cheap chain; exec-mask friendly)
#define TOP4_INS(key, t0, t1, t2, t3)                   \
  if ((key) > t3) {                                     \
    t3 = (key);                                         \
    ull tmp_;                                           \
    if (t3 > t2) { tmp_ = t2; t2 = t3; t3 = tmp_; }     \
    if (t2 > t1) { tmp_ = t1; t1 = t2; t2 = tmp_; }     \
    if (t1 > t0) { tmp_ = t0; t0 = t1; t1 = tmp_; }     \
  }

// drain-stop pop extraction (proven R8-R12): entries written are the exact
// sorted global top-`written` of the wave's candidate multiset.
__device__ __forceinline__ void extract_list(ull t0, ull t1, ull t2, ull t3,
                                             ull* dst, int lane) {
  int supplied = 0, written = 0;
  for (int o = 0; o < DEPTH_; ++o) {
    ull m = wave_maxkey(t0);
    if (m == 0ull) break;
    int dn = 0;
    if (t0 == m) {  // unique keys -> exactly one lane
      t0 = t1; t1 = t2; t2 = t3; t3 = 0;
      if (++supplied == 4) dn = 1;  // lane emptied: beyond here unsafe
    }
    if (lane == 0) dst[o] = m;
    ++written;
    if (__any(dn)) break;
  }
  for (int o = written + lane; o < DEPTH_; o += 64) dst[o] = 0ull;
}

// ---- phase 1: wave-per-column exact top-L lists; fused 2-col scan ----
// grid: B*8 blocks; block = (batch, octant of 25 cols); wave w: cols w, w+16.
__global__ __launch_bounds__(1024) void kinit(const float* __restrict__ pred_boxes,
                                              const float* __restrict__ gt_boxes,
                                              const void* __restrict__ gt_mask,
                                              char* __restrict__ ws) {
  __shared__ float4 s_p[K_];  // 64 KB staged pred boxes
  const int blk = blockIdx.x;
  const int b = blk >> 3, oct = blk & 7;
  const int tid = threadIdx.x, lane = tid & 63, wid = tid >> 6;
  const int msk8 = *(const int*)(ws + WS_FLAG);
  const float4* p4 = (const float4*)pred_boxes + (size_t)b * K_;
  const float4* g4 = (const float4*)gt_boxes + (size_t)b * G_;

  for (int i = tid; i < K_; i += 1024) s_p[i] = p4[i];
  __syncthreads();

  const int base = oct * 25;
  const int colA = base + wid;            // wid in [0,16)
  const int colB = base + 16 + wid;       // valid col iff wid < 9
  const bool hasB = (wid < 9);
  ull* wtop = (ull*)(ws + WS_TOP);

  int vA, vB = 0;
  if (msk8) vA = ((const unsigned char*)gt_mask)[(size_t)b * G_ + colA] != 0;
  else      vA = ((const int*)gt_mask)[(size_t)b * G_ + colA] != 0;
  if (hasB) {
    if (msk8) vB = ((const unsigned char*)gt_mask)[(size_t)b * G_ + colB] != 0;
    else      vB = ((const int*)gt_mask)[(size_t)b * G_ + colB] != 0;
  }

  float4 gbA, gbB;
  float gAA = 0.f, gAB = 0.f;
  if (vA) { gbA = g4[colA]; gAA = box_area(gbA); }
  if (vB) { gbB = g4[colB]; gAB = box_area(gbB); }

  ull a0 = 0, a1 = 0, a2 = 0, a3 = 0;
  ull b0 = 0, b1 = 0, b2 = 0, b3 = 0;
  if (vA | vB) {  // wave-uniform
#pragma unroll 4
    for (int k = lane; k < K_; k += 64) {
      float4 pb = s_p[k];
      float ar = box_area(pb);  // shared by both columns
      if (vA) {
        float iou = iou_ab(pb, ar, gbA, gAA);
        ull e = ((ull)__float_as_uint(iou) << 12) | (ull)(4095 - k);
        TOP4_INS(e, a0, a1, a2, a3);
      }
      if (vB) {
        float iou = iou_ab(pb, ar, gbB, gAB);
        ull e = ((ull)__float_as_uint(iou) << 12) | (ull)(4095 - k);
        TOP4_INS(e, b0, b1, b2, b3);
      }
    }
  }
  {
    ull* dstA = wtop + ((size_t)b * G_ + colA) * DEPTH_;
    if (vA) extract_list(a0, a1, a2, a3, dstA, lane);
    else    for (int o = lane; o < DEPTH_; o += 64) dstA[o] = 0ull;
  }
  if (hasB) {
    ull* dstB = wtop + ((size_t)b * G_ + colB) * DEPTH_;
    if (vB) extract_list(b0, b1, b2, b3, dstB, lane);
    else    for (int o = lane; o < DEPTH_; o += 64) dstB[o] = 0ull;
  }
}

// ---- phase 2+3 fused: greedy matching (wave 0, quad-pop) + epilogue ----
// waves 1-15 compute the match-independent softplus base during the matching.
__global__ __launch_bounds__(1024) void kmerged(
    const float* __restrict__ pred_boxes, const float* __restrict__ obj_logits,
    const float* __restrict__ cls_logits, const float* __restrict__ gt_boxes,
    const int* __restrict__ gt_labels, char* __restrict__ ws) {
  __shared__ float s_gx[G_], s_gy[G_], s_gz[G_], s_gw[G_], s_garea[G_];
  __shared__ unsigned char s_rowused[4096];   // padded: speculative reads safe
  __shared__ ull s_toplist[G_][DEPTH_ + 1];   // stride 33: bank-spread walks
  __shared__ int s_mp[G_];
  __shared__ unsigned short s_mg[G_];
  __shared__ int s_cnt;
  __shared__ float s_red[NW_];
  const int b = blockIdx.x;
  const int tid = threadIdx.x, lane = tid & 63, wid = tid >> 6;
  const float4* p4 = (const float4*)pred_boxes + (size_t)b * K_;
  const float4* g4 = (const float4*)gt_boxes + (size_t)b * G_;
  const ull* wtop = (const ull*)(ws + WS_TOP);
  const float* ol = obj_logits + (size_t)b * K_;

  for (int g = tid; g < G_; g += 1024) {
    float4 gb = g4[g];
    s_gx[g] = gb.x; s_gy[g] = gb.y; s_gz[g] = gb.z; s_gw[g] = gb.w;
    s_garea[g] = box_area(gb);
  }
  for (int k = tid; k < 4096; k += 1024) s_rowused[k] = 0;
  // cooperative toplist copy (coalesced)
  for (int i = tid; i < G_ * DEPTH_; i += 1024)
    s_toplist[i / DEPTH_][i % DEPTH_] = wtop[((size_t)b * G_) * DEPTH_ + i];
  __syncthreads();

  float obj = 0.f;  // waves 1-15: softplus base (match-independent), overlapped
  if (wid != 0) {
    for (int k = tid - 64; k < K_; k += 960) {
      float x = ol[k];
      obj += fmaxf(x, 0.f) + log1pf(expf(-fabsf(x)));  // softplus(x)
    }
  }

  if (wid == 0) {
    ull key0 = 0, key1 = 0, key2 = 0, key3 = 0;
    int ptr0 = DEPTH_, ptr1 = DEPTH_, ptr2 = DEPTH_, ptr3 = DEPTH_;
    int cloc = 0;
#define SLOTINIT(S)                                                        \
    { int col = S * 64 + lane;                                             \
      if (col < G_) {                                                      \
        ull h_ = s_toplist[col][0];                                        \
        if (h_ != 0ull) {                                                  \
          key##S = (h_ << 8) | (ull)(255 - col); ptr##S = 1; ++cloc; } } }
    SLOTINIT(0) SLOTINIT(1) SLOTINIT(2) SLOTINIT(3)
#undef SLOTINIT
    for (int off = 32; off > 0; off >>= 1) cloc += __shfl_xor(cloc, off);
    const int cnt = cloc;
    if (lane == 0) s_cnt = cnt;

    for (int step = 0; step < cnt;) {
      // lane-local sorted-desc 4-list of slot keys (5-comparator network)
      ull v0 = key0, v1 = key1, v2 = key2, v3 = key3, x;
      if (v1 > v0) { x = v0; v0 = v1; v1 = x; }
      if (v3 > v2) { x = v2; v2 = v3; v3 = x; }
      if (v2 > v0) { x = v0; v0 = v2; v2 = x; }
      if (v3 > v1) { x = v1; v1 = v3; v3 = x; }
      if (v2 > v1) { x = v1; v1 = v2; v2 = x; }
      // wave top-4 reduce (exact): 6 bitonic-merge butterfly stages
      merge4_stage(v0, v1, v2, v3, 32);
      merge4_stage(v0, v1, v2, v3, 16);
      merge4_stage(v0, v1, v2, v3, 8);
      merge4_stage(v0, v1, v2, v3, 4);
      merge4_stage(v0, v1, v2, v3, 2);
      merge4_stage(v0, v1, v2, v3, 1);
      const int P0 = 4095 - (int)((v0 >> 8) & 0xFFF), G0 = 255 - (int)(v0 & 0xFF);
      const int P1 = 4095 - (int)((v1 >> 8) & 0xFFF), G1 = 255 - (int)(v1 & 0xFF);
      const int P2 = 4095 - (int)((v2 >> 8) & 0xFFF), G2 = 255 - (int)(v2 & 0xFF);
      const int P3 = 4095 - (int)((v3 >> 8) & 0xFFF), G3 = 255 - (int)(v3 & 0xFF);
      // accept maximal prefix with pairwise-distinct rows: demotions from pop i
      // only touch columns whose best row == p_i, so each next prefix key stays
      // the exact global max (cols distinct automatically: one key per column).
      const int lim = cnt - step;
      const bool a2 = (v1 != 0ull) && (P1 != P0) && (lim > 1);
      const bool a3 = a2 && (v2 != 0ull) && (P2 != P0) && (P2 != P1) && (lim > 2);
      const bool a4 = a3 && (v3 != 0ull) && (P3 != P0) && (P3 != P1) && (P3 != P2) && (lim > 3);
      const int nacc = 1 + (int)a2 + (int)a3 + (int)a4;
      if (lane == 0) {
        s_mp[step] = P0; s_mg[step] = (unsigned short)G0; s_rowused[P0] = 1;
        if (a2) { s_mp[step + 1] = P1; s_mg[step + 1] = (unsigned short)G1; s_rowused[P1] = 1; }
        if (a3) { s_mp[step + 2] = P2; s_mg[step + 2] = (unsigned short)G2; s_rowused[P2] = 1; }
        if (a4) { s_mp[step + 3] = P3; s_mg[step + 3] = (unsigned short)G3; s_rowused[P3] = 1; }
      }
      __builtin_amdgcn_wave_barrier();
      const int gA = G0, gB = a2 ? G1 : -1, gC = a3 ? G2 : -1, gD = a4 ? G3 : -1;
      const int pA = P0, pB = a2 ? P1 : -1, pC = a3 ? P2 : -1, pD = a4 ? P3 : -1;
      int need = 0;
#define DEMOTE(S)                                                           \
      { int col = S * 64 + lane; ull kk = key##S;                           \
        if (kk != 0ull) {                                                   \
          if (col == gA || col == gB || col == gC || col == gD) {           \
            key##S = 0ull;                                                  \
          } else {                                                          \
            int krow = 4095 - (int)((kk >> 8) & 0xFFF);                     \
            if (krow == pA || krow == pB || krow == pC || krow == pD) {     \
              ull nk = 0ull; int np = ptr##S;                               \
              while (np < DEPTH_) {                                         \
                ull e0 = s_toplist[col][np];                                \
                ull e1 = (np + 1 < DEPTH_) ? s_toplist[col][np + 1] : 0ull; \
                int pr0 = 4095 - (int)((e0 >> 12) & 0xFFF);                 \
                int pr1 = 4095 - (int)((e1 >> 12) & 0xFFF);                 \
                unsigned char u0 = s_rowused[pr0];                          \
                unsigned char u1 = s_rowused[pr1];                          \
                if (e0 == 0ull) { np = DEPTH_; break; }                     \
                if (!u0) { nk = (e0 << 8) | (ull)(255 - col); np += 1; break; } \
                if (e1 == 0ull) { np = DEPTH_; break; }                     \
                if (!u1) { nk = (e1 << 8) | (ull)(255 - col); np += 2; break; } \
                np += 2;                                                    \
              }                                                             \
              ptr##S = np; key##S = nk;                                     \
              if (nk == 0ull) need |= (1 << S); } } } }
      DEMOTE(0) DEMOTE(1) DEMOTE(2) DEMOTE(3)
#undef DEMOTE
      // exact fallback: full rescan over unused rows; rank-sort refill.
      // Written prefix = exact sorted top-prefix (cutoff = min over full
      // lanes of rank(their 4th)+1 — same drain-stop guarantee as pops).
      while (__any(need)) {
        unsigned long long bal = __ballot(need != 0);
        int src = (int)__builtin_ctzll(bal);
        int myslot = need ? __builtin_ctz(need) : 0;
        int slot = __shfl(myslot, src);
        int col = slot * 64 + src;
        float4 gb = make_float4(s_gx[col], s_gy[col], s_gz[col], s_gw[col]);
        float gA2 = s_garea[col];
        ull t0 = 0, t1 = 0, t2 = 0, t3 = 0;
#pragma unroll 2
        for (int k = lane; k < K_; k += 64) {
          if (!s_rowused[k]) {
            float4 pb = p4[k];
            float iou = iou_ab(pb, box_area(pb), gb, gA2);
            ull e = ((ull)__float_as_uint(iou) << 12) | (ull)(4095 - k);
            TOP4_INS(e, t0, t1, t2, t3);
          }
        }
        // exact global ranks via pipelined broadcast loop (keys unique)
        int r0 = 0, r1 = 0, r2 = 0, r3 = 0;
        for (int i = 0; i < 64; ++i) {
          ull o0 = __shfl(t0, i), o1 = __shfl(t1, i);
          ull o2 = __shfl(t2, i), o3 = __shfl(t3, i);
          r0 += (o0 > t0) + (o1 > t0) + (o2 > t0) + (o3 > t0);
          r1 += (o0 > t1) + (o1 > t1) + (o2 > t1) + (o3 > t1);
          r2 += (o0 > t2) + (o1 > t2) + (o2 > t2) + (o3 > t2);
          r3 += (o0 > t3) + (o1 > t3) + (o2 > t3) + (o3 > t3);
        }
        int cut = (t3 != 0ull) ? (r3 + 1) : 0x7FFFFFFF;
        int nc = (t0 != 0ull) + (t1 != 0ull) + (t2 != 0ull) + (t3 != 0ull);
        for (int off = 32; off > 0; off >>= 1) {
          int oc = __shfl_xor(cut, off);
          cut = (oc < cut) ? oc : cut;
          nc += __shfl_xor(nc, off);
        }
        const int Lf = (cut < DEPTH_) ? cut : DEPTH_;
        const int zstart = (Lf < nc) ? Lf : nc;
        if (t0 != 0ull && r0 < Lf) s_toplist[col][r0] = t0;
        if (t1 != 0ull && r1 < Lf) s_toplist[col][r1] = t1;
        if (t2 != 0ull && r2 < Lf) s_toplist[col][r2] = t2;
        if (t3 != 0ull && r3 < Lf) s_toplist[col][r3] = t3;
        for (int o = lane; o < DEPTH_; o += 64)
          if (o >= zstart) s_toplist[col][o] = 0ull;
        __builtin_amdgcn_wave_barrier();
        ull newhead = s_toplist[col][0];  // bank-broadcast read
        if (lane == src) {
          ull nk = (newhead << 8) | (ull)(255 - col);  // newhead != 0: rows remain
          if (slot == 0) { key0 = nk; ptr0 = 1; }
          else if (slot == 1) { key1 = nk; ptr1 = 1; }
          else if (slot == 2) { key2 = nk; ptr2 = 1; }
          else { key3 = nk; ptr3 = 1; }
          need &= ~(1 << slot);
        }
        __builtin_amdgcn_wave_barrier();
      }
      step += nacc;
    }
  }
  __syncthreads();

  // ---- epilogue: CIoU + CE over matches; objectness = base - matched x ----
  const int cnt = s_cnt;
  float lbox = 0.f, lcls = 0.f;
  for (int i = tid; i < cnt; i += 1024) {
    int p = s_mp[i], g = s_mg[i];
    float4 pb = p4[p];
    float4 gb = make_float4(s_gx[g], s_gy[g], s_gz[g], s_gw[g]);
    lbox += ciou_loss(pb, gb);
    int label = gt_labels[(size_t)b * G_ + g];
    const float* lg = cls_logits + ((size_t)b * K_ + p) * C_;
    float m = -1e30f;
    for (int cc = 0; cc < C_; ++cc) m = fmaxf(m, lg[cc]);
    float s = 0.f;
    for (int cc = 0; cc < C_; ++cc) s += expf(lg[cc] - m);
    lcls += (m + logf(s)) - lg[label];
  }
  // correction: subtract x for matched rows (base computed pre-barrier)
  for (int k = tid; k < K_; k += 1024) {
    if (s_rowused[k]) obj -= ol[k];
  }
  lbox = block_sum(lbox, s_red);
  lcls = block_sum(lcls, s_red);
  obj = block_sum(obj, s_red);
  if (tid == 0) {
    float* partials = (float*)(ws + WS_PART);
    float n = (float)cnt;
    float denom = fmaxf(n, 1.f);
    partials[b * 4 + 0] = lbox / denom;
    partials[b * 4 + 1] = lcls / denom;
    partials[b * 4 + 2] = obj;
    partials[b * 4 + 3] = (n > 0.f) ? 1.f : 0.f;
  }
}

__global__ void kfinal(const char* __restrict__ ws, float* __restrict__ out) {
  int b = threadIdx.x;  // 64 threads, one wave
  const float* partials = (const float*)(ws + WS_PART);
  float lb = partials[b * 4 + 0], lc = partials[b * 4 + 1];
  float ob = partials[b * 4 + 2], hf = partials[b * 4 + 3];
  float sb = lb * hf, sc = lc * hf, sh = hf, so = ob;
  for (int off = 32; off > 0; off >>= 1) {
    sb += __shfl_xor(sb, off);
    sc += __shfl_xor(sc, off);
    sh += __shfl_xor(sh, off);
    so += __shfl_xor(so, off);
  }
  if (b == 0) {
    float nb = fmaxf(sh, 1.f);
    float box = sb / nb, cls = sc / nb;
    float obj = so / (float)(B_ * K_);
    out[0] = 5.f * box + cls + obj;
    out[1] = box;
    out[2] = cls;
    out[3] = obj;
  }
}

extern "C" void kernel_launch(void* const* d_in, const int* in_sizes, int n_in,
                              void* d_out, int out_size, void* d_ws, size_t ws_size,
                              hipStream_t stream) {
  const float* pred_boxes = (const float*)d_in[0];
  const float* obj_logits = (const float*)d_in[1];
  const float* cls_logits = (const float*)d_in[2];
  const float* gt_boxes = (const float*)d_in[3];
  const int* gt_labels = (const int*)d_in[4];
  const void* gt_mask = d_in[5];
  float* out = (float*)d_out;
  char* ws = (char*)d_ws;

  hipLaunchKernelGGL(kdetect, dim3(1), dim3(64), 0, stream,
                     (const unsigned char*)gt_mask, (int*)(ws + WS_FLAG));
  hipLaunchKernelGGL(kinit, dim3(B_ * 8), dim3(1024), 0, stream,
                     pred_boxes, gt_boxes, gt_mask, ws);
  hipLaunchKernelGGL(kmerged, dim3(B_), dim3(1024), 0, stream,
                     pred_boxes, obj_logits, cls_logits, gt_boxes, gt_labels, ws);
  hipLaunchKernelGGL(kfinal, dim3(1), dim3(64), 0, stream, ws, out);
}

// Round 18
// 250.394 us; speedup vs baseline: 1.1940x; 1.0099x over previous
//
#include <hip/hip_runtime.h>
#include <math.h>

#define B_ 64
#define K_ 4000
#define G_ 200
#define C_ 91
#define EPS_ 1e-9f
#define NW_ 16
#define DEPTH_ 32
typedef unsigned long long ull;

// ws layout (byte offsets); total use ~3.6 MB
#define WS_FLAG 0
#define WS_PART 256        // 64*4 f32
#define WS_TOP 327680      // 64*200*32 ull = 3.28 MB (exact top-L lists, L<=32)

// list key: (iou_bits << 12) | (4095 - p)   — iou desc, then p asc; always > 0
// full key: (list << 8) | (255 - g)         — iou desc, p asc, g asc == argmax flat order
__device__ __forceinline__ float box_area(float4 a) {
#pragma clang fp contract(off)
  return fmaxf(a.z - a.x, 0.f) * fmaxf(a.w - a.y, 0.f);
}

// IoU; contract(off) => bit-identical across init and rescan
__device__ __forceinline__ float iou_ab(float4 a, float aA, float4 b, float aB) {
#pragma clang fp contract(off)
  float tlx = fmaxf(a.x, b.x), tly = fmaxf(a.y, b.y);
  float brx = fminf(a.z, b.z), bry = fminf(a.w, b.w);
  float w = fmaxf(brx - tlx, 0.f), h = fmaxf(bry - tly, 0.f);
  float inter = w * h;
  float uni = fmaxf(aA + aB - inter, EPS_);
  return inter / uni;
}

__device__ __forceinline__ float ciou_loss(float4 p, float4 g) {
  float tlx = fmaxf(p.x, g.x), tly = fmaxf(p.y, g.y);
  float brx = fminf(p.z, g.z), bry = fminf(p.w, g.w);
  float w = fmaxf(brx - tlx, 0.f), h = fmaxf(bry - tly, 0.f);
  float inter = w * h;
  float areaP = fmaxf(p.z - p.x, 0.f) * fmaxf(p.w - p.y, 0.f);
  float areaG = fmaxf(g.z - g.x, 0.f) * fmaxf(g.w - g.y, 0.f);
  float iou = inter / fmaxf(areaP + areaG - inter, EPS_);
  float px = (p.x + p.z) * 0.5f, py = (p.y + p.w) * 0.5f;
  float tx = (g.x + g.z) * 0.5f, ty = (g.y + g.w) * 0.5f;
  float rho2 = (px - tx) * (px - tx) + (py - ty) * (py - ty);
  float ex = fmaxf(p.z, g.z) - fminf(p.x, g.x);
  float ey = fmaxf(p.w, g.w) - fminf(p.y, g.y);
  float c2 = fmaxf(ex * ex + ey * ey, EPS_);
  float pw = fmaxf(p.z - p.x, EPS_), ph = fmaxf(p.w - p.y, EPS_);
  float tw = fmaxf(g.z - g.x, EPS_), th = fmaxf(g.w - g.y, EPS_);
  float dat = atanf(tw / th) - atanf(pw / ph);
  float v = (4.0f / (float)(M_PI * M_PI)) * dat * dat;
  float alpha = v / ((1.f - iou) + v + EPS_);
  return 1.f - (iou - rho2 / c2 - alpha * v);
}

// gt_mask layout detector (int8 bool vs 4-byte elems) — unchanged (passed R1-R17)
__global__ void kdetect(const unsigned char* m8, int* flag) {
  int b = threadIdx.x;
  int ok = 1;
  const unsigned char* r = m8 + b * G_;
  if (r[0] != 1) ok = 0;
  int seen0 = 0;
  for (int g = 0; g < G_; ++g) {
    unsigned char c = r[g];
    if (c > 1) { ok = 0; break; }
    if (c == 0) seen0 = 1;
    else if (seen0) { ok = 0; break; }
  }
  int all = __all(ok);
  if (b == 0) *flag = all ? 1 : 0;
}

__device__ __forceinline__ float block_sum(float v, float* s_red) {
  for (int off = 32; off > 0; off >>= 1) v += __shfl_xor(v, off);
  int lane = threadIdx.x & 63, wid = threadIdx.x >> 6;
  if (lane == 0) s_red[wid] = v;
  __syncthreads();
  float r = 0.f;
  if (wid == 0) {
    float t = (lane < NW_) ? s_red[lane] : 0.f;
    for (int off = 32; off > 0; off >>= 1) t += __shfl_xor(t, off);
    r = t;
  }
  __syncthreads();
  return r;  // valid at tid 0
}

__device__ __forceinline__ ull wave_maxkey(ull k) {
  for (int off = 32; off > 0; off >>= 1) {
    ull o = __shfl_xor(k, off);
    if (o > k) k = o;
  }
  return k;
}

// one butterfly stage of wave top-4 reduce: merge own sorted-desc 4-list with
// partner's (bitonic merge, keep top 4, re-sorted desc). All lanes converge
// to the identical exact global top-4 after 6 stages.
__device__ __forceinline__ void merge4_stage(ull& v0, ull& v1, ull& v2, ull& v3,
                                             int off) {
  ull w0 = __shfl_xor(v0, off), w1 = __shfl_xor(v1, off);
  ull w2 = __shfl_xor(v2, off), w3 = __shfl_xor(v3, off);
  ull t0 = v0 > w3 ? v0 : w3;
  ull t1 = v1 > w2 ? v1 : w2;
  ull t2 = v2 > w1 ? v2 : w1;
  ull t3 = v3 > w0 ? v3 : w0;
  ull x;
  if (t2 > t0) { x = t0; t0 = t2; t2 = x; }
  if (t3 > t1) { x = t1; t1 = t3; t3 = x; }
  if (t1 > t0) { x = t0; t0 = t1; t1 = x; }
  if (t3 > t2) { x = t2; t2 = t3; t3 = x; }
  v0 = t0; v1 = t1; v2 = t2; v3 = t3;
}

// register-resident sorted-desc top-4 insert (cheap chain; exec-mask friendly)
#define TOP4_INS(key, t0, t1, t2, t3)                   \
  if ((key) > t3) {                                     \
    t3 = (key);                                         \
    ull tmp_;                                           \
    if (t3 > t2) { tmp_ = t2; t2 = t3; t3 = tmp_; }     \
    if (t2 > t1) { tmp_ = t1; t1 = t2; t2 = tmp_; }     \
    if (t1 > t0) { tmp_ = t0; t0 = t1; t1 = tmp_; }     \
  }

// drain-stop pop extraction (proven R8-R17): entries written are the exact
// sorted global top-`written` of the wave's candidate multiset.
__device__ __forceinline__ void extract_list(ull t0, ull t1, ull t2, ull t3,
                                             ull* dst, int lane) {
  int supplied = 0, written = 0;
  for (int o = 0; o < DEPTH_; ++o) {
    ull m = wave_maxkey(t0);
    if (m == 0ull) break;
    int dn = 0;
    if (t0 == m) {  // unique keys -> exactly one lane
      t0 = t1; t1 = t2; t2 = t3; t3 = 0;
      if (++supplied == 4) dn = 1;  // lane emptied: beyond here unsafe
    }
    if (lane == 0) dst[o] = m;
    ++written;
    if (__any(dn)) break;
  }
  for (int o = written + lane; o < DEPTH_; o += 64) dst[o] = 0ull;
}

// ---- phase 1: wave-per-column exact top-L lists; fused 2-col scan ----
// grid: B*8 blocks; block = (batch, octant of 25 cols); wave w: cols w, w+16.
__global__ __launch_bounds__(1024) void kinit(const float* __restrict__ pred_boxes,
                                              const float* __restrict__ gt_boxes,
                                              const void* __restrict__ gt_mask,
                                              char* __restrict__ ws) {
  __shared__ float4 s_p[K_];     // 64 KB staged pred boxes
  __shared__ float s_parea[K_];  // 16 KB precomputed areas (80KB -> 2 blk/CU)
  const int blk = blockIdx.x;
  const int b = blk >> 3, oct = blk & 7;
  const int tid = threadIdx.x, lane = tid & 63, wid = tid >> 6;
  const int msk8 = *(const int*)(ws + WS_FLAG);
  const float4* p4 = (const float4*)pred_boxes + (size_t)b * K_;
  const float4* g4 = (const float4*)gt_boxes + (size_t)b * G_;

  for (int i = tid; i < K_; i += 1024) {
    float4 pb = p4[i];
    s_p[i] = pb;
    s_parea[i] = box_area(pb);  // same bits as inline box_area at use sites
  }
  __syncthreads();

  const int base = oct * 25;
  const int colA = base + wid;            // wid in [0,16)
  const int colB = base + 16 + wid;       // valid col iff wid < 9
  const bool hasB = (wid < 9);
  ull* wtop = (ull*)(ws + WS_TOP);

  int vA, vB = 0;
  if (msk8) vA = ((const unsigned char*)gt_mask)[(size_t)b * G_ + colA] != 0;
  else      vA = ((const int*)gt_mask)[(size_t)b * G_ + colA] != 0;
  if (hasB) {
    if (msk8) vB = ((const unsigned char*)gt_mask)[(size_t)b * G_ + colB] != 0;
    else      vB = ((const int*)gt_mask)[(size_t)b * G_ + colB] != 0;
  }

  float4 gbA, gbB;
  float gAA = 0.f, gAB = 0.f;
  if (vA) { gbA = g4[colA]; gAA = box_area(gbA); }
  if (vB) { gbB = g4[colB]; gAB = box_area(gbB); }

  ull a0 = 0, a1 = 0, a2 = 0, a3 = 0;
  ull b0 = 0, b1 = 0, b2 = 0, b3 = 0;
  if (vA | vB) {  // wave-uniform
#pragma unroll 4
    for (int k = lane; k < K_; k += 64) {
      float4 pb = s_p[k];
      float ar = s_parea[k];  // precomputed, shared by both columns
      if (vA) {
        float iou = iou_ab(pb, ar, gbA, gAA);
        ull e = ((ull)__float_as_uint(iou) << 12) | (ull)(4095 - k);
        TOP4_INS(e, a0, a1, a2, a3);
      }
      if (vB) {
        float iou = iou_ab(pb, ar, gbB, gAB);
        ull e = ((ull)__float_as_uint(iou) << 12) | (ull)(4095 - k);
        TOP4_INS(e, b0, b1, b2, b3);
      }
    }
  }
  {
    ull* dstA = wtop + ((size_t)b * G_ + colA) * DEPTH_;
    if (vA) extract_list(a0, a1, a2, a3, dstA, lane);
    else    for (int o = lane; o < DEPTH_; o += 64) dstA[o] = 0ull;
  }
  if (hasB) {
    ull* dstB = wtop + ((size_t)b * G_ + colB) * DEPTH_;
    if (vB) extract_list(b0, b1, b2, b3, dstB, lane);
    else    for (int o = lane; o < DEPTH_; o += 64) dstB[o] = 0ull;
  }
}

// ---- phase 2+3 fused: greedy matching (wave 0, quad-pop) + epilogue ----
// waves 1-15 compute the match-independent softplus base during the matching.
__global__ __launch_bounds__(1024) void kmerged(
    const float* __restrict__ pred_boxes, const float* __restrict__ obj_logits,
    const float* __restrict__ cls_logits, const float* __restrict__ gt_boxes,
    const int* __restrict__ gt_labels, char* __restrict__ ws) {
  __shared__ float s_gx[G_], s_gy[G_], s_gz[G_], s_gw[G_], s_garea[G_];
  __shared__ unsigned char s_rowused[4096];   // padded: speculative reads safe
  __shared__ ull s_toplist[G_][DEPTH_ + 1];   // stride 33: bank-spread walks
  __shared__ int s_mp[G_];
  __shared__ unsigned short s_mg[G_];
  __shared__ int s_cnt;
  __shared__ float s_red[NW_];
  const int b = blockIdx.x;
  const int tid = threadIdx.x, lane = tid & 63, wid = tid >> 6;
  const float4* p4 = (const float4*)pred_boxes + (size_t)b * K_;
  const float4* g4 = (const float4*)gt_boxes + (size_t)b * G_;
  const ull* wtop = (const ull*)(ws + WS_TOP);
  const float* ol = obj_logits + (size_t)b * K_;

  for (int g = tid; g < G_; g += 1024) {
    float4 gb = g4[g];
    s_gx[g] = gb.x; s_gy[g] = gb.y; s_gz[g] = gb.z; s_gw[g] = gb.w;
    s_garea[g] = box_area(gb);
  }
  for (int k = tid; k < 4096; k += 1024) s_rowused[k] = 0;
  // cooperative toplist copy (coalesced)
  for (int i = tid; i < G_ * DEPTH_; i += 1024)
    s_toplist[i / DEPTH_][i % DEPTH_] = wtop[((size_t)b * G_) * DEPTH_ + i];
  __syncthreads();

  float obj = 0.f;  // waves 1-15: softplus base (match-independent), overlapped
  if (wid != 0) {
    for (int k = tid - 64; k < K_; k += 960) {
      float x = ol[k];
      obj += fmaxf(x, 0.f) + log1pf(expf(-fabsf(x)));  // softplus(x)
    }
  }

  if (wid == 0) {
    ull key0 = 0, key1 = 0, key2 = 0, key3 = 0;
    int ptr0 = DEPTH_, ptr1 = DEPTH_, ptr2 = DEPTH_, ptr3 = DEPTH_;
    int cloc = 0;
#define SLOTINIT(S)                                                        \
    { int col = S * 64 + lane;                                             \
      if (col < G_) {                                                      \
        ull h_ = s_toplist[col][0];                                        \
        if (h_ != 0ull) {                                                  \
          key##S = (h_ << 8) | (ull)(255 - col); ptr##S = 1; ++cloc; } } }
    SLOTINIT(0) SLOTINIT(1) SLOTINIT(2) SLOTINIT(3)
#undef SLOTINIT
    for (int off = 32; off > 0; off >>= 1) cloc += __shfl_xor(cloc, off);
    const int cnt = cloc;
    if (lane == 0) s_cnt = cnt;

    for (int step = 0; step < cnt;) {
      // lane-local sorted-desc 4-list of slot keys (5-comparator network)
      ull v0 = key0, v1 = key1, v2 = key2, v3 = key3, x;
      if (v1 > v0) { x = v0; v0 = v1; v1 = x; }
      if (v3 > v2) { x = v2; v2 = v3; v3 = x; }
      if (v2 > v0) { x = v0; v0 = v2; v2 = x; }
      if (v3 > v1) { x = v1; v1 = v3; v3 = x; }
      if (v2 > v1) { x = v1; v1 = v2; v2 = x; }
      // wave top-4 reduce (exact): 6 bitonic-merge butterfly stages
      merge4_stage(v0, v1, v2, v3, 32);
      merge4_stage(v0, v1, v2, v3, 16);
      merge4_stage(v0, v1, v2, v3, 8);
      merge4_stage(v0, v1, v2, v3, 4);
      merge4_stage(v0, v1, v2, v3, 2);
      merge4_stage(v0, v1, v2, v3, 1);
      const int P0 = 4095 - (int)((v0 >> 8) & 0xFFF), G0 = 255 - (int)(v0 & 0xFF);
      const int P1 = 4095 - (int)((v1 >> 8) & 0xFFF), G1 = 255 - (int)(v1 & 0xFF);
      const int P2 = 4095 - (int)((v2 >> 8) & 0xFFF), G2 = 255 - (int)(v2 & 0xFF);
      const int P3 = 4095 - (int)((v3 >> 8) & 0xFFF), G3 = 255 - (int)(v3 & 0xFF);
      // accept maximal prefix with pairwise-distinct rows (proof in R12; exact)
      const int lim = cnt - step;
      const bool a2 = (v1 != 0ull) && (P1 != P0) && (lim > 1);
      const bool a3 = a2 && (v2 != 0ull) && (P2 != P0) && (P2 != P1) && (lim > 2);
      const bool a4 = a3 && (v3 != 0ull) && (P3 != P0) && (P3 != P1) && (P3 != P2) && (lim > 3);
      const int nacc = 1 + (int)a2 + (int)a3 + (int)a4;
      if (lane == 0) {
        s_mp[step] = P0; s_mg[step] = (unsigned short)G0; s_rowused[P0] = 1;
        if (a2) { s_mp[step + 1] = P1; s_mg[step + 1] = (unsigned short)G1; s_rowused[P1] = 1; }
        if (a3) { s_mp[step + 2] = P2; s_mg[step + 2] = (unsigned short)G2; s_rowused[P2] = 1; }
        if (a4) { s_mp[step + 3] = P3; s_mg[step + 3] = (unsigned short)G3; s_rowused[P3] = 1; }
      }
      __builtin_amdgcn_wave_barrier();
      const int gA = G0, gB = a2 ? G1 : -1, gC = a3 ? G2 : -1, gD = a4 ? G3 : -1;
      const int pA = P0, pB = a2 ? P1 : -1, pC = a3 ? P2 : -1, pD = a4 ? P3 : -1;
      int need = 0;
#define DEMOTE(S)                                                           \
      { int col = S * 64 + lane; ull kk = key##S;                           \
        if (kk != 0ull) {                                                   \
          if (col == gA || col == gB || col == gC || col == gD) {           \
            key##S = 0ull;                                                  \
          } else {                                                          \
            int krow = 4095 - (int)((kk >> 8) & 0xFFF);                     \
            if (krow == pA || krow == pB || krow == pC || krow == pD) {     \
              ull nk = 0ull; int np = ptr##S;                               \
              while (np < DEPTH_) {                                         \
                ull e0 = s_toplist[col][np];                                \
                ull e1 = (np + 1 < DEPTH_) ? s_toplist[col][np + 1] : 0ull; \
                int pr0 = 4095 - (int)((e0 >> 12) & 0xFFF);                 \
                int pr1 = 4095 - (int)((e1 >> 12) & 0xFFF);                 \
                unsigned char u0 = s_rowused[pr0];                          \
                unsigned char u1 = s_rowused[pr1];                          \
                if (e0 == 0ull) { np = DEPTH_; break; }                     \
                if (!u0) { nk = (e0 << 8) | (ull)(255 - col); np += 1; break; } \
                if (e1 == 0ull) { np = DEPTH_; break; }                     \
                if (!u1) { nk = (e1 << 8) | (ull)(255 - col); np += 2; break; } \
                np += 2;                                                    \
              }                                                             \
              ptr##S = np; key##S = nk;                                     \
              if (nk == 0ull) need |= (1 << S); } } } }
      DEMOTE(0) DEMOTE(1) DEMOTE(2) DEMOTE(3)
#undef DEMOTE
      // exact fallback: full rescan over unused rows, refilling up to TWO
      // exhausted columns per pass (shared scan; refills don't touch
      // s_rowused, so each column's candidate set is identical to the
      // serial-order version -> bit-identical lists).
      while (__any(need)) {
        unsigned long long bal = __ballot(need != 0);
        int src1 = (int)__builtin_ctzll(bal);
        int myslot = need ? __builtin_ctz(need) : 0;
        int slot1 = __shfl(myslot, src1);
        int need2m = (lane == src1) ? (need & ~(1 << slot1)) : need;
        unsigned long long bal2 = __ballot(need2m != 0);
        const bool has2 = (bal2 != 0ull);
        int src2 = 0, slot2 = 0, col2 = 0;
        float4 gb2; float gA2b = 0.f;
        if (has2) {
          src2 = (int)__builtin_ctzll(bal2);
          int myslot2 = need2m ? __builtin_ctz(need2m) : 0;
          slot2 = __shfl(myslot2, src2);
          col2 = slot2 * 64 + src2;
          gb2 = make_float4(s_gx[col2], s_gy[col2], s_gz[col2], s_gw[col2]);
          gA2b = s_garea[col2];
        }
        const int col1 = slot1 * 64 + src1;
        float4 gb1 = make_float4(s_gx[col1], s_gy[col1], s_gz[col1], s_gw[col1]);
        float gA2a = s_garea[col1];
        ull t0 = 0, t1 = 0, t2 = 0, t3 = 0;      // col1
        ull u0 = 0, u1 = 0, u2 = 0, u3 = 0;      // col2
#pragma unroll 2
        for (int k = lane; k < K_; k += 64) {
          if (!s_rowused[k]) {
            float4 pb = p4[k];
            float ar = box_area(pb);
            {
              float iou = iou_ab(pb, ar, gb1, gA2a);
              ull e = ((ull)__float_as_uint(iou) << 12) | (ull)(4095 - k);
              TOP4_INS(e, t0, t1, t2, t3);
            }
            if (has2) {
              float iou = iou_ab(pb, ar, gb2, gA2b);
              ull e = ((ull)__float_as_uint(iou) << 12) | (ull)(4095 - k);
              TOP4_INS(e, u0, u1, u2, u3);
            }
          }
        }
        // exact global ranks via pipelined broadcast loop (keys unique)
        int r0 = 0, r1 = 0, r2 = 0, r3 = 0;
        int q0 = 0, q1 = 0, q2 = 0, q3 = 0;
        for (int i = 0; i < 64; ++i) {
          ull o0 = __shfl(t0, i), o1 = __shfl(t1, i);
          ull o2 = __shfl(t2, i), o3 = __shfl(t3, i);
          r0 += (o0 > t0) + (o1 > t0) + (o2 > t0) + (o3 > t0);
          r1 += (o0 > t1) + (o1 > t1) + (o2 > t1) + (o3 > t1);
          r2 += (o0 > t2) + (o1 > t2) + (o2 > t2) + (o3 > t2);
          r3 += (o0 > t3) + (o1 > t3) + (o2 > t3) + (o3 > t3);
          if (has2) {
            ull z0 = __shfl(u0, i), z1 = __shfl(u1, i);
            ull z2 = __shfl(u2, i), z3 = __shfl(u3, i);
            q0 += (z0 > u0) + (z1 > u0) + (z2 > u0) + (z3 > u0);
            q1 += (z0 > u1) + (z1 > u1) + (z2 > u1) + (z3 > u1);
            q2 += (z0 > u2) + (z1 > u2) + (z2 > u2) + (z3 > u2);
            q3 += (z0 > u3) + (z1 > u3) + (z2 > u3) + (z3 > u3);
          }
        }
        // col1 cut/scatter (drain-stop-equivalent prefix, proven R11-R17)
        {
          int cut = (t3 != 0ull) ? (r3 + 1) : 0x7FFFFFFF;
          int nc = (t0 != 0ull) + (t1 != 0ull) + (t2 != 0ull) + (t3 != 0ull);
          for (int off = 32; off > 0; off >>= 1) {
            int oc = __shfl_xor(cut, off);
            cut = (oc < cut) ? oc : cut;
            nc += __shfl_xor(nc, off);
          }
          const int Lf = (cut < DEPTH_) ? cut : DEPTH_;
          const int zstart = (Lf < nc) ? Lf : nc;
          if (t0 != 0ull && r0 < Lf) s_toplist[col1][r0] = t0;
          if (t1 != 0ull && r1 < Lf) s_toplist[col1][r1] = t1;
          if (t2 != 0ull && r2 < Lf) s_toplist[col1][r2] = t2;
          if (t3 != 0ull && r3 < Lf) s_toplist[col1][r3] = t3;
          for (int o = lane; o < DEPTH_; o += 64)
            if (o >= zstart) s_toplist[col1][o] = 0ull;
        }
        if (has2) {
          int cut = (u3 != 0ull) ? (q3 + 1) : 0x7FFFFFFF;
          int nc = (u0 != 0ull) + (u1 != 0ull) + (u2 != 0ull) + (u3 != 0ull);
          for (int off = 32; off > 0; off >>= 1) {
            int oc = __shfl_xor(cut, off);
            cut = (oc < cut) ? oc : cut;
            nc += __shfl_xor(nc, off);
          }
          const int Lf = (cut < DEPTH_) ? cut : DEPTH_;
          const int zstart = (Lf < nc) ? Lf : nc;
          if (u0 != 0ull && q0 < Lf) s_toplist[col2][q0] = u0;
          if (u1 != 0ull && q1 < Lf) s_toplist[col2][q1] = u1;
          if (u2 != 0ull && q2 < Lf) s_toplist[col2][q2] = u2;
          if (u3 != 0ull && q3 < Lf) s_toplist[col2][q3] = u3;
          for (int o = lane; o < DEPTH_; o += 64)
            if (o >= zstart) s_toplist[col2][o] = 0ull;
        }
        __builtin_amdgcn_wave_barrier();
        ull nh1 = s_toplist[col1][0];  // bank-broadcast reads
        ull nh2 = has2 ? s_toplist[col2][0] : 0ull;
        if (lane == src1) {
          ull nk = (nh1 << 8) | (ull)(255 - col1);  // nh1 != 0: rows remain
          if (slot1 == 0) { key0 = nk; ptr0 = 1; }
          else if (slot1 == 1) { key1 = nk; ptr1 = 1; }
          else if (slot1 == 2) { key2 = nk; ptr2 = 1; }
          else { key3 = nk; ptr3 = 1; }
          need &= ~(1 << slot1);
        }
        if (has2 && lane == src2) {
          ull nk = (nh2 << 8) | (ull)(255 - col2);
          if (slot2 == 0) { key0 = nk; ptr0 = 1; }
          else if (slot2 == 1) { key1 = nk; ptr1 = 1; }
          else if (slot2 == 2) { key2 = nk; ptr2 = 1; }
          else { key3 = nk; ptr3 = 1; }
          need &= ~(1 << slot2);
        }
        __builtin_amdgcn_wave_barrier();
      }
      step += nacc;
    }
  }
  __syncthreads();

  // ---- epilogue: CIoU + CE over matches; objectness = base - matched x ----
  const int cnt = s_cnt;
  float lbox = 0.f, lcls = 0.f;
  for (int i = tid; i < cnt; i += 1024) {
    int p = s_mp[i], g = s_mg[i];
    float4 pb = p4[p];
    float4 gb = make_float4(s_gx[g], s_gy[g], s_gz[g], s_gw[g]);
    lbox += ciou_loss(pb, gb);
    int label = gt_labels[(size_t)b * G_ + g];
    const float* lg = cls_logits + ((size_t)b * K_ + p) * C_;
    float m = -1e30f;
    for (int cc = 0; cc < C_; ++cc) m = fmaxf(m, lg[cc]);
    float s = 0.f;
    for (int cc = 0; cc < C_; ++cc) s += expf(lg[cc] - m);
    lcls += (m + logf(s)) - lg[label];
  }
  // correction: subtract x for matched rows (base computed pre-barrier)
  for (int k = tid; k < K_; k += 1024) {
    if (s_rowused[k]) obj -= ol[k];
  }
  lbox = block_sum(lbox, s_red);
  lcls = block_sum(lcls, s_red);
  obj = block_sum(obj, s_red);
  if (tid == 0) {
    float* partials = (float*)(ws + WS_PART);
    float n = (float)cnt;
    float denom = fmaxf(n, 1.f);
    partials[b * 4 + 0] = lbox / denom;
    partials[b * 4 + 1] = lcls / denom;
    partials[b * 4 + 2] = obj;
    partials[b * 4 + 3] = (n > 0.f) ? 1.f : 0.f;
  }
}

__global__ void kfinal(const char* __restrict__ ws, float* __restrict__ out) {
  int b = threadIdx.x;  // 64 threads, one wave
  const float* partials = (const float*)(ws + WS_PART);
  float lb = partials[b * 4 + 0], lc = partials[b * 4 + 1];
  float ob = partials[b * 4 + 2], hf = partials[b * 4 + 3];
  float sb = lb * hf, sc = lc * hf, sh = hf, so = ob;
  for (int off = 32; off > 0; off >>= 1) {
    sb += __shfl_xor(sb, off);
    sc += __shfl_xor(sc, off);
    sh += __shfl_xor(sh, off);
    so += __shfl_xor(so, off);
  }
  if (b == 0) {
    float nb = fmaxf(sh, 1.f);
    float box = sb / nb, cls = sc / nb;
    float obj = so / (float)(B_ * K_);
    out[0] = 5.f * box + cls + obj;
    out[1] = box;
    out[2] = cls;
    out[3] = obj;
  }
}

extern "C" void kernel_launch(void* const* d_in, const int* in_sizes, int n_in,
                              void* d_out, int out_size, void* d_ws, size_t ws_size,
                              hipStream_t stream) {
  const float* pred_boxes = (const float*)d_in[0];
  const float* obj_logits = (const float*)d_in[1];
  const float* cls_logits = (const float*)d_in[2];
  const float* gt_boxes = (const float*)d_in[3];
  const int* gt_labels = (const int*)d_in[4];
  const void* gt_mask = d_in[5];
  float* out = (float*)d_out;
  char* ws = (char*)d_ws;

  hipLaunchKernelGGL(kdetect, dim3(1), dim3(64), 0, stream,
                     (const unsigned char*)gt_mask, (int*)(ws + WS_FLAG));
  hipLaunchKernelGGL(kinit, dim3(B_ * 8), dim3(1024), 0, stream,
                     pred_boxes, gt_boxes, gt_mask, ws);
  hipLaunchKernelGGL(kmerged, dim3(B_), dim3(1024), 0, stream,
                     pred_boxes, obj_logits, cls_logits, gt_boxes, gt_labels, ws);
  hipLaunchKernelGGL(kfinal, dim3(1), dim3(64), 0, stream, ws, out);
}